// Round 1
// 4083.892 us; speedup vs baseline: 1.2497x; 1.2497x over previous
//
#include <hip/hip_runtime.h>
#include <math.h>

typedef unsigned short u16; // bf16 bits
typedef short bf16x8 __attribute__((ext_vector_type(8)));
typedef float f32x4 __attribute__((ext_vector_type(4)));

__device__ __forceinline__ float bf2f(u16 u){ return __uint_as_float(((unsigned)u)<<16); }
__device__ __forceinline__ u16 f2bf(float f){
  unsigned u = __float_as_uint(f);
  u += 0x7fffu + ((u>>16)&1u);   // RNE
  return (u16)(u>>16);
}
__device__ __forceinline__ float gelu_f(float x){ return 0.5f*x*(1.0f+erff(x*0.7071067811865476f)); }

// async global->LDS, 16B per lane; LDS dest = wave-uniform base + lane*16
__device__ __forceinline__ void gload16(const void* g, void* l){
  __builtin_amdgcn_global_load_lds((const __attribute__((address_space(1))) void*)g,
                                   (__attribute__((address_space(3))) void*)l, 16, 0, 0);
}

__device__ __forceinline__ float block_sum(float v, float* sh){
  #pragma unroll
  for (int o=32;o;o>>=1) v += __shfl_down(v,o,64);
  int w = threadIdx.x>>6, lane = threadIdx.x&63;
  __syncthreads();
  if (lane==0) sh[w]=v;
  __syncthreads();
  return sh[0]+sh[1]+sh[2]+sh[3];
}
__device__ __forceinline__ float block_max(float v, float* sh){
  #pragma unroll
  for (int o=32;o;o>>=1) v = fmaxf(v, __shfl_down(v,o,64));
  int w = threadIdx.x>>6, lane = threadIdx.x&63;
  __syncthreads();
  if (lane==0) sh[w]=v;
  __syncthreads();
  return fmaxf(fmaxf(sh[0],sh[1]),fmaxf(sh[2],sh[3]));
}

// ---------------- fast MFMA GEMM: C = act(alpha * A@B^T + bias) -----------
// A [M][K] bf16 (lda), B [N][K] bf16 (ldb).  Tile = (FM*32) x (FN*32), BK=64.
// 4 waves as 2x2; per wave FM x FN fragments of 16x16 (mfma 16x16x32).
// Staging: global_load_lds dwordx4, linear LDS rows of 128B, with XOR chunk
// swizzle applied BOTH on the per-lane global source and on ds_read (rule #21)
// so column-fragment reads spread across all 8 16B chunks (balanced banks).
template<int FM,int FN,int OF32,int ACC,int ACT>
__global__ __launch_bounds__(256) void gemm2_k(
    const u16* __restrict__ A, const u16* __restrict__ Bm, void* __restrict__ Cv,
    const float* __restrict__ bias,
    int K,int lda,int ldb,int ldc,float alpha,int z0,
    long sAz,long oAb,long oAh, long sBz,long oBb,long oBh, long sCz,long oCb,long oCh)
{
  constexpr int BM = FM*32, BN = FN*32;
  int zz = blockIdx.z; int z = z0+zz; int bb = z>>4, hh = z&15;
  const u16* Ap = A  + (long)zz*sAz + (long)bb*oAb + (long)hh*oAh;
  const u16* Bp = Bm + (long)zz*sBz + (long)bb*oBb + (long)hh*oBh;
  long coff = (long)zz*sCz + (long)bb*oCb + (long)hh*oCh;
  int m0 = blockIdx.y*BM, n0 = blockIdx.x*BN;
  __shared__ __align__(16) u16 As[BM][64];
  __shared__ __align__(16) u16 Bs[BN][64];
  u16* AsF = &As[0][0]; u16* BsF = &Bs[0][0];
  int tid = threadIdx.x, w = tid>>6, l = tid&63;
  int q = l>>4, m16 = l&15;
  int wr = w>>1, wc = w&1;
  // staging geometry: each call fills 32 rows (4096B); wave w owns 8 rows.
  int sr  = w*8 + (l>>3);              // row within 32-row chunk (mod-8 = (l>>3)&7)
  int sch = (l&7) ^ ((l>>3)&7);        // inverse-swizzled source chunk
  int s7  = m16 & 7;                   // read-side row&7 (frag rows step by 16)

  f32x4 acc[FM][FN];
  #pragma unroll
  for (int i=0;i<FM;i++)
    #pragma unroll
    for (int j=0;j<FN;j++) acc[i][j] = (f32x4){0.f,0.f,0.f,0.f};

  int aRow = wr*(FM*16) + m16;
  int bRow = wc*(FN*16) + m16;

  for (int k0=0;k0<K;k0+=64){
    __syncthreads();                    // LDS safe to overwrite
    #pragma unroll
    for (int c=0;c<FM;c++)
      gload16(Ap + (long)(m0 + c*32 + sr)*lda + k0 + sch*8, AsF + c*2048 + w*512);
    #pragma unroll
    for (int c=0;c<FN;c++)
      gload16(Bp + (long)(n0 + c*32 + sr)*ldb + k0 + sch*8, BsF + c*2048 + w*512);
    __syncthreads();                    // compiler drains vmcnt(0) before barrier
    #pragma unroll
    for (int kh=0;kh<2;kh++){
      bf16x8 afr[FM], bfr[FN];
      #pragma unroll
      for (int i=0;i<FM;i++)
        afr[i] = *(const bf16x8*)(AsF + (aRow + i*16)*64 + (((kh<<2)|q) ^ s7)*8);
      #pragma unroll
      for (int j=0;j<FN;j++)
        bfr[j] = *(const bf16x8*)(BsF + (bRow + j*16)*64 + (((kh<<2)|q) ^ s7)*8);
      #pragma unroll
      for (int i=0;i<FM;i++)
        #pragma unroll
        for (int j=0;j<FN;j++)
          acc[i][j] = __builtin_amdgcn_mfma_f32_16x16x32_bf16(afr[i], bfr[j], acc[i][j], 0,0,0);
    }
  }
  #pragma unroll
  for (int j=0;j<FN;j++){
    int n = n0 + wc*(FN*16) + j*16 + m16;
    float bv = bias ? bias[n] : 0.0f;
    #pragma unroll
    for (int i=0;i<FM;i++){
      #pragma unroll
      for (int r=0;r<4;r++){
        int m = m0 + wr*(FM*16) + i*16 + q*4 + r;   // C/D: col=lane&15, row=quad*4+reg
        float v = acc[i][j][r]*alpha + bv;
        if (ACT==1) v = gelu_f(v);
        long ci = coff + (long)m*ldc + n;
        if (OF32){
          float* C = (float*)Cv;
          if (ACC) C[ci] += v; else C[ci] = v;
        } else {
          ((u16*)Cv)[ci] = f2bf(v);
        }
      }
    }
  }
}

// ------------- weight transpose+convert: in [K][N] f32 -> out [N][K] bf16 --
__global__ __launch_bounds__(256) void wtc_k(const float* __restrict__ in,
                                             u16* __restrict__ out, int N, int K){
  __shared__ float tile[64][65];
  int bx = blockIdx.x, by = blockIdx.y;     // bx over N/64, by over K/64
  int t = threadIdx.x, r = t>>6, c = t&63;
  const float* ip = in + (long)(by*64)*N + bx*64;
  #pragma unroll
  for (int i=0;i<16;i++) tile[i*4+r][c] = ip[(long)(i*4+r)*N + c];
  __syncthreads();
  u16* op = out + (long)(bx*64)*K + by*64;
  #pragma unroll
  for (int i=0;i<16;i++) op[(long)(i*4+r)*K + c] = f2bf(tile[c][i*4+r]);
}

// ---------------- LayerNorm (row over D=1024), f32 in, f32 stats -----------
template<int ACCXC,int HAS_OUT,int OUTF32>
__global__ __launch_bounds__(256) void ln_k(const float* __restrict__ in,
    const float* __restrict__ g, const float* __restrict__ b,
    float* __restrict__ xc, void* __restrict__ out)
{
  __shared__ float sh[4];
  long row = blockIdx.x;
  int tid = threadIdx.x;
  float x[4];
  #pragma unroll
  for (int i=0;i<4;i++) x[i] = in[row*1024 + tid + 256*i];
  float s = x[0]+x[1]+x[2]+x[3];
  float mean = block_sum(s, sh) * (1.0f/1024.0f);
  float ss = 0.f;
  #pragma unroll
  for (int i=0;i<4;i++){ float d = x[i]-mean; ss += d*d; }
  float var = block_sum(ss, sh) * (1.0f/1024.0f);
  float rstd = rsqrtf(var + 1e-5f);
  #pragma unroll
  for (int i=0;i<4;i++){
    int col = tid + 256*i;
    long idx = row*1024 + col;
    float val = (x[i]-mean)*rstd*g[col];
    if (b) val += b[col];
    if (ACCXC) xc[idx] += val;
    if (HAS_OUT){
      if (OUTF32) ((float*)out)[idx] = val;
      else ((u16*)out)[idx] = f2bf(val);
    }
  }
}

// softmax over a 1024-wide f32 score row; write (+) or subtract (-) into bf16 P
template<int SIGN>
__global__ __launch_bounds__(256) void softmax_k(const float* __restrict__ S, u16* __restrict__ P){
  __shared__ float sh[4];
  long zz = blockIdx.y, qv = blockIdx.x;
  const float* srow = S + zz*1048576 + qv*1024;
  u16* prow = P + zz*1048576 + qv*1024;
  int tid = threadIdx.x;
  float x[4];
  #pragma unroll
  for (int i=0;i<4;i++) x[i] = srow[tid+256*i];
  float m = fmaxf(fmaxf(x[0],x[1]),fmaxf(x[2],x[3]));
  m = block_max(m, sh);
  float e[4]; float s = 0.f;
  #pragma unroll
  for (int i=0;i<4;i++){ e[i] = expf(x[i]-m); s += e[i]; }
  s = block_sum(s, sh);
  float inv = 1.0f/s;
  #pragma unroll
  for (int i=0;i<4;i++){
    int col = tid+256*i;
    float val = e[i]*inv;
    if (SIGN>0) prow[col] = f2bf(val);
    else { float o = bf2f(prow[col]); prow[col] = f2bf(o-val); }
  }
}

__global__ void cvt_k(const float* __restrict__ x, float* __restrict__ xc){
  long i = (long)blockIdx.x*256 + threadIdx.x;
  xc[i] = x[i];
}

// vavgT[z=(b,h)][dh][s] = 0.5*(v1'+v2')
__global__ void vavg_k(const u16* __restrict__ qkv1, const u16* __restrict__ qkv2,
                       u16* __restrict__ vavgT){
  long idx = (long)blockIdx.x*256 + threadIdx.x;
  int s  = idx & 1023;
  int dh = (idx>>10)&63;
  int h  = (idx>>16)&15;
  int b  = (int)(idx>>20);
  long off = ((long)(b*1024+s))*3072 + 2048 + h*64 + dh;
  float v = 0.5f*(bf2f(qkv1[off]) + bf2f(qkv2[off]));
  vavgT[idx] = f2bf(v);
}

// abar[d] = b1[d] + sigma_l * sum_r U[d][r] * (sum_j V[r][j])
__global__ void abar_k(const float* __restrict__ sig, const float* __restrict__ U,
                       const float* __restrict__ V, const float* __restrict__ b1,
                       float* __restrict__ abar){
  __shared__ float vs[4];
  int tid = threadIdx.x, w = tid>>6, lane = tid&63;
  float p = 0.f;
  #pragma unroll
  for (int i=0;i<16;i++) p += V[w*1024 + lane + 64*i];
  #pragma unroll
  for (int o=32;o;o>>=1) p += __shfl_down(p,o,64);
  if (lane==0) vs[w] = p;
  __syncthreads();
  float sg = sig[0];
  for (int d=tid; d<1024; d+=256){
    float a = 0.f;
    #pragma unroll
    for (int r=0;r<4;r++) a += U[d*4+r]*vs[r];
    abar[d] = b1[d] + sg*a;
  }
}

// x1bar[n] = bp1[n] + sum_{k<512} abar[k]*Wp1[k][n];  x2bar likewise
__global__ void bar1_k(const float* __restrict__ abar,
                       const float* __restrict__ Wp1, const float* __restrict__ bp1,
                       const float* __restrict__ Wp2, const float* __restrict__ bp2,
                       float* __restrict__ x1bar, float* __restrict__ x2bar){
  int n = blockIdx.x*256 + threadIdx.x;
  float s1 = bp1[n], s2 = bp2[n];
  for (int k=0;k<512;k++){
    s1 += abar[k]     * Wp1[(long)k*1024 + n];
    s2 += abar[512+k] * Wp2[(long)k*1024 + n];
  }
  x1bar[n] = s1; x2bar[n] = s2;
}

// qbias[n] = sum_{k<1024} xbar[k]*Wqkv[k][n] for n<1024 (q cols), else 0.
// 3072-wide so it folds directly into the qkv GEMM as a bias vector.
__global__ void bar2_k(const float* __restrict__ xbar, const float* __restrict__ Wq,
                       float* __restrict__ qbias){
  int n = blockIdx.x*256 + threadIdx.x;   // grid 12 -> 3072
  float s = 0.f;
  if (n < 1024){
    for (int k=0;k<1024;k++) s += xbar[k]*Wq[(long)k*3072 + n];
  }
  qbias[n] = s;
}

extern "C" void kernel_launch(void* const* d_in, const int* in_sizes, int n_in,
                              void* d_out, int out_size, void* d_ws, size_t ws_size,
                              hipStream_t stream){
  const float* X    = (const float*)d_in[0];
  const float* SIG  = (const float*)d_in[1];
  const float* U    = (const float*)d_in[2];
  const float* V    = (const float*)d_in[3];
  const float* Wqkv1= (const float*)d_in[4];
  const float* Wqkv2= (const float*)d_in[5];
  const float* Wp1  = (const float*)d_in[6];
  const float* bp1  = (const float*)d_in[7];
  const float* Wp2  = (const float*)d_in[8];
  const float* bp2  = (const float*)d_in[9];
  const float* Wo   = (const float*)d_in[10];
  const float* bo   = (const float*)d_in[11];
  const float* gO   = (const float*)d_in[12];
  const float* bO   = (const float*)d_in[13];
  const float* g1   = (const float*)d_in[14];
  const float* b1   = (const float*)d_in[15];
  const float* g2   = (const float*)d_in[16];
  const float* b2   = (const float*)d_in[17];
  const float* Wm1  = (const float*)d_in[18];
  const float* bm1  = (const float*)d_in[19];
  const float* Wm2  = (const float*)d_in[20];
  const float* bm2  = (const float*)d_in[21];
  const float* gf   = (const float*)d_in[22];
  const float* bfv  = (const float*)d_in[23];
  (void)in_sizes; (void)n_in; (void)out_size; (void)ws_size;

  // ---- workspace layout with time-aliasing (unchanged footprint, <68.1 MiB) ----
  char* p = (char*)d_ws;
  float* xc     = (float*)(p + 0);         // [0, 8M)    residual stream f32
  u16* qkv1     = (u16*)(p + 8388608);     // [8M, 20M)  bf16 (q cols include qbar)
  u16* qkv2     = (u16*)(p + 20971520);    // [20M, 32M) bf16
  u16* bufA     = (u16*)(p + 33554432);    // a_bf / attnout / h2
  u16* bufB     = (u16*)(p + 37748736);    // x1w
  u16* bufC     = (u16*)(p + 41943040);    // x2w / vavgT
  float* Sbuf   = (float*)(p + 46137344);  // 16M: scores (attention phase)
  u16* mid      = (u16*)(p + 46137344);    //   aliases Sbuf (MLP phase)
  float* projout= (float*)(p + 46137344);  //   aliases Sbuf (proj phase)
  u16* Pbf      = (u16*)(p + 62914560);    // 8M bf16 P
  float* abar   = (float*)(p + 71303168);
  float* x1bar  = (float*)(p + 71307264);
  float* x2bar  = (float*)(p + 71311360);
  // bf16-transposed weights, aliased into time-dead regions:
  //  - Wp/Wqkv live in the Sbuf region (dead until attention starts)
  u16* wpT1     = (u16*)(p + 46137344);                // 1M
  u16* wpT2     = (u16*)(p + 46137344 + 1048576);      // 1M
  u16* wqkvT1   = (u16*)(p + 46137344 + 2097152);      // 6M
  u16* wqkvT2   = (u16*)(p + 46137344 + 8388608);      // 6M  (ends +14M)
  float* qbias1 = (float*)(p + 46137344 + 14680064);   // 12K (dead after qkv GEMM)
  float* qbias2 = (float*)(p + 46137344 + 14692352);
  //  - Wo/Wm1/Wm2 live in the qkv1/qkv2 region (dead after last QK GEMM)
  u16* woT      = (u16*)(p + 8388608);                 // 2M
  u16* wm1T     = (u16*)(p + 8388608 + 2097152);       // 8M
  u16* wm2T     = (u16*)(p + 8388608 + 10485760);      // 8M (ends at 26M < 32M)

  u16* a_bf    = bufA; u16* attnout = bufA; u16* h2 = bufA;
  u16* x1w     = bufB;
  u16* x2w     = bufC; u16* vavgT   = bufC;

  const float SCALE = 0.125f;

  cvt_k<<<8192,256,0,stream>>>(X, xc);
  for (int l=0;l<4;l++){
    // exact f32 constant path: abar = b1 + adapt; x{1,2}bar; qbias{1,2}
    abar_k<<<1,256,0,stream>>>(SIG+l, U+(long)l*4096, V+(long)l*4096, b1+l*1024, abar);
    bar1_k<<<4,256,0,stream>>>(abar, Wp1+(long)l*524288, bp1+l*1024,
                               Wp2+(long)l*524288, bp2+l*1024, x1bar, x2bar);
    bar2_k<<<12,256,0,stream>>>(x1bar, Wqkv1+(long)l*3145728, qbias1);
    bar2_k<<<12,256,0,stream>>>(x2bar, Wqkv2+(long)l*3145728, qbias2);
    // weight convert+transpose for the pre-attention GEMMs
    wtc_k<<<dim3(16,8), 256,0,stream>>>(Wp1+(long)l*524288,  wpT1, 1024, 512);
    wtc_k<<<dim3(16,8), 256,0,stream>>>(Wp2+(long)l*524288,  wpT2, 1024, 512);
    wtc_k<<<dim3(48,16),256,0,stream>>>(Wqkv1+(long)l*3145728, wqkvT1, 3072, 1024);
    wtc_k<<<dim3(48,16),256,0,stream>>>(Wqkv2+(long)l*3145728, wqkvT2, 3072, 1024);
    // centered path: a' = LN(xc)*g1 (no beta, no adapt) -> bf16
    ln_k<0,1,0><<<2048,256,0,stream>>>(xc, g1+l*1024, nullptr, nullptr, a_bf);
    // x1' = a'[:, :512] @ Wp1 ; x2' = a'[:, 512:] @ Wp2  (bias folded into bars)
    gemm2_k<2,4,0,0,0><<<dim3(8,32,1),256,0,stream>>>(a_bf,     wpT1, x1w, nullptr,
        512, 1024, 512, 1024, 1.0f, 0, 0,0,0, 0,0,0, 0,0,0);
    gemm2_k<2,4,0,0,0><<<dim3(8,32,1),256,0,stream>>>(a_bf+512, wpT2, x2w, nullptr,
        512, 1024, 512, 1024, 1.0f, 0, 0,0,0, 0,0,0, 0,0,0);
    // qkv' = x' @ Wqkv + [qbar | 0 | 0]  (qbar folded here -> QK needs no aadd)
    gemm2_k<4,4,0,0,0><<<dim3(24,16,1),256,0,stream>>>(x1w, wqkvT1, qkv1, qbias1,
        1024, 1024, 1024, 3072, 1.0f, 0, 0,0,0, 0,0,0, 0,0,0);
    gemm2_k<4,4,0,0,0><<<dim3(24,16,1),256,0,stream>>>(x2w, wqkvT2, qkv2, qbias2,
        1024, 1024, 1024, 3072, 1.0f, 0, 0,0,0, 0,0,0, 0,0,0);
    vavg_k<<<8192,256,0,stream>>>(qkv1,qkv2,vavgT);
    // attention in 8 chunks of 4 (b,h) batches
    for (int zc=0;zc<8;zc++){
      int z0 = zc*4;
      gemm2_k<4,4,1,0,0><<<dim3(8,8,4),256,0,stream>>>(qkv1, qkv1+1024, Sbuf, nullptr,
          64, 3072, 3072, 1024, SCALE, z0, 0,3145728,64, 0,3145728,64, 1048576,0,0);
      softmax_k<1><<<dim3(1024,4),256,0,stream>>>(Sbuf,Pbf);
      gemm2_k<4,4,1,0,0><<<dim3(8,8,4),256,0,stream>>>(qkv2, qkv2+1024, Sbuf, nullptr,
          64, 3072, 3072, 1024, SCALE, z0, 0,3145728,64, 0,3145728,64, 1048576,0,0);
      softmax_k<-1><<<dim3(1024,4),256,0,stream>>>(Sbuf,Pbf);
      // out = P @ vavg^T  (v-bar contributes 0: rows of P sum to 0)
      gemm2_k<4,2,0,0,0><<<dim3(1,8,4),256,0,stream>>>(Pbf, vavgT, attnout, nullptr,
          1024, 1024, 1024, 1024, 1.0f, z0, 1048576,0,0, 0,1048576,65536, 0,1048576,64);
    }
    // convert post-attention weights into the now-dead qkv region
    wtc_k<<<dim3(16,16),256,0,stream>>>(Wo +(long)l*1048576, woT,  1024, 1024);
    wtc_k<<<dim3(64,16),256,0,stream>>>(Wm1+(long)l*4194304, wm1T, 4096, 1024);
    wtc_k<<<dim3(16,64),256,0,stream>>>(Wm2+(long)l*4194304, wm2T, 1024, 4096);
    // proj (f32 out) + LN + residual
    gemm2_k<2,4,1,0,0><<<dim3(8,32,1),256,0,stream>>>(attnout, woT, projout, bo+l*1024,
        1024, 1024, 1024, 1024, 1.0f, 0, 0,0,0, 0,0,0, 0,0,0);
    ln_k<1,0,0><<<2048,256,0,stream>>>(projout, gO+l*1024, bO+l*1024, xc, nullptr);
    // MLP
    ln_k<0,1,0><<<2048,256,0,stream>>>(xc, g2+l*1024, b2+l*1024, nullptr, h2);
    gemm2_k<4,4,0,0,1><<<dim3(32,16,1),256,0,stream>>>(h2, wm1T, mid, bm1+l*4096,
        1024, 1024, 1024, 4096, 1.0f, 0, 0,0,0, 0,0,0, 0,0,0);
    gemm2_k<2,4,1,1,0><<<dim3(8,32,1),256,0,stream>>>(mid, wm2T, (void*)xc, bm2+l*1024,
        4096, 4096, 4096, 1024, 1.0f, 0, 0,0,0, 0,0,0, 0,0,0);
  }
  ln_k<0,1,1><<<2048,256,0,stream>>>(xc, gf, bfv, nullptr, (float*)d_out);
}

// Round 2
// 1585.505 us; speedup vs baseline: 3.2189x; 2.5758x over previous
//
#include <hip/hip_runtime.h>
#include <math.h>

typedef unsigned short u16; // bf16 bits
typedef short bf16x8 __attribute__((ext_vector_type(8)));
typedef float f32x4 __attribute__((ext_vector_type(4)));

__device__ __forceinline__ float bf2f(u16 u){ return __uint_as_float(((unsigned)u)<<16); }
__device__ __forceinline__ u16 f2bf(float f){
  unsigned u = __float_as_uint(f);
  u += 0x7fffu + ((u>>16)&1u);   // RNE
  return (u16)(u>>16);
}
__device__ __forceinline__ float gelu_f(float x){ return 0.5f*x*(1.0f+erff(x*0.7071067811865476f)); }

// async global->LDS, 16B per lane; LDS dest = wave-uniform base + lane*16
__device__ __forceinline__ void gload16(const void* g, void* l){
  __builtin_amdgcn_global_load_lds((const __attribute__((address_space(1))) void*)g,
                                   (__attribute__((address_space(3))) void*)l, 16, 0, 0);
}

__device__ __forceinline__ float block_sum(float v, float* sh){
  #pragma unroll
  for (int o=32;o;o>>=1) v += __shfl_down(v,o,64);
  int w = threadIdx.x>>6, lane = threadIdx.x&63;
  __syncthreads();
  if (lane==0) sh[w]=v;
  __syncthreads();
  return sh[0]+sh[1]+sh[2]+sh[3];
}

// ---------------- fast MFMA GEMM: C = act(alpha * A@B^T + bias) -----------
// A [M][K] bf16 (lda), B [N][K] bf16 (ldb).  Tile = (FM*32) x (FN*32), BK=64.
// 4 waves as 2x2; per wave FM x FN fragments of 16x16 (mfma 16x16x32).
template<int FM,int FN,int OF32,int ACC,int ACT>
__global__ __launch_bounds__(256) void gemm2_k(
    const u16* __restrict__ A, const u16* __restrict__ Bm, void* __restrict__ Cv,
    const float* __restrict__ bias,
    int K,int lda,int ldb,int ldc,float alpha,int z0,
    long sAz,long oAb,long oAh, long sBz,long oBb,long oBh, long sCz,long oCb,long oCh)
{
  constexpr int BM = FM*32, BN = FN*32;
  int zz = blockIdx.z; int z = z0+zz; int bb = z>>4, hh = z&15;
  const u16* Ap = A  + (long)zz*sAz + (long)bb*oAb + (long)hh*oAh;
  const u16* Bp = Bm + (long)zz*sBz + (long)bb*oBb + (long)hh*oBh;
  long coff = (long)zz*sCz + (long)bb*oCb + (long)hh*oCh;
  int m0 = blockIdx.y*BM, n0 = blockIdx.x*BN;
  __shared__ __align__(16) u16 As[BM][64];
  __shared__ __align__(16) u16 Bs[BN][64];
  u16* AsF = &As[0][0]; u16* BsF = &Bs[0][0];
  int tid = threadIdx.x, w = tid>>6, l = tid&63;
  int q = l>>4, m16 = l&15;
  int wr = w>>1, wc = w&1;
  int sr  = w*8 + (l>>3);              // row within 32-row chunk
  int sch = (l&7) ^ ((l>>3)&7);        // inverse-swizzled source chunk
  int s7  = m16 & 7;                   // read-side row&7

  f32x4 acc[FM][FN];
  #pragma unroll
  for (int i=0;i<FM;i++)
    #pragma unroll
    for (int j=0;j<FN;j++) acc[i][j] = (f32x4){0.f,0.f,0.f,0.f};

  int aRow = wr*(FM*16) + m16;
  int bRow = wc*(FN*16) + m16;

  for (int k0=0;k0<K;k0+=64){
    __syncthreads();
    #pragma unroll
    for (int c=0;c<FM;c++)
      gload16(Ap + (long)(m0 + c*32 + sr)*lda + k0 + sch*8, AsF + c*2048 + w*512);
    #pragma unroll
    for (int c=0;c<FN;c++)
      gload16(Bp + (long)(n0 + c*32 + sr)*ldb + k0 + sch*8, BsF + c*2048 + w*512);
    __syncthreads();
    #pragma unroll
    for (int kh=0;kh<2;kh++){
      bf16x8 afr[FM], bfr[FN];
      #pragma unroll
      for (int i=0;i<FM;i++)
        afr[i] = *(const bf16x8*)(AsF + (aRow + i*16)*64 + (((kh<<2)|q) ^ s7)*8);
      #pragma unroll
      for (int j=0;j<FN;j++)
        bfr[j] = *(const bf16x8*)(BsF + (bRow + j*16)*64 + (((kh<<2)|q) ^ s7)*8);
      #pragma unroll
      for (int i=0;i<FM;i++)
        #pragma unroll
        for (int j=0;j<FN;j++)
          acc[i][j] = __builtin_amdgcn_mfma_f32_16x16x32_bf16(afr[i], bfr[j], acc[i][j], 0,0,0);
    }
  }
  #pragma unroll
  for (int j=0;j<FN;j++){
    int n = n0 + wc*(FN*16) + j*16 + m16;
    float bv = bias ? bias[n] : 0.0f;
    #pragma unroll
    for (int i=0;i<FM;i++){
      #pragma unroll
      for (int r=0;r<4;r++){
        int m = m0 + wr*(FM*16) + i*16 + q*4 + r;   // C/D: col=lane&15, row=quad*4+reg
        float v = acc[i][j][r]*alpha + bv;
        if (ACT==1) v = gelu_f(v);
        long ci = coff + (long)m*ldc + n;
        if (OF32){
          float* C = (float*)Cv;
          if (ACC) C[ci] += v; else C[ci] = v;
        } else {
          ((u16*)Cv)[ci] = f2bf(v);
        }
      }
    }
  }
}

// ---------------- flash attention: P = sm(Q1K1')-sm(Q2K2'), O = P @ Vavg' --
// per-stream online softmax; O = O1/l1 - O2/l2 (vbar cancels between streams)
// block: 4 waves, 64 q-rows (16 per wave); loops 16 kv-tiles of 64.
// swapped QK^T: mfma(K,Q) -> S[k][q]; per-lane q = lane&15, k in-lane (16 vals)
__device__ __forceinline__ void flash_stream(
    const u16* Kl, const u16* Vl, u16* Plw,
    bf16x8 qa, bf16x8 qb, int qd, int m16,
    float& mrun, float& lsum, f32x4* O)
{
  int r7 = m16 & 7;
  f32x4 s[4];
  #pragma unroll
  for (int f=0;f<4;f++){
    s[f] = (f32x4){0.f,0.f,0.f,0.f};
    int row = f*16 + m16;
    bf16x8 ka = *(const bf16x8*)(Kl + row*64 + ((qd    ) ^ r7)*8);
    bf16x8 kb = *(const bf16x8*)(Kl + row*64 + ((4 + qd) ^ r7)*8);
    s[f] = __builtin_amdgcn_mfma_f32_16x16x32_bf16(ka, qa, s[f], 0,0,0);
    s[f] = __builtin_amdgcn_mfma_f32_16x16x32_bf16(kb, qb, s[f], 0,0,0);
  }
  float sc[16]; float pmax = -1e30f;
  #pragma unroll
  for (int f=0;f<4;f++)
    #pragma unroll
    for (int r=0;r<4;r++){ float v = s[f][r]*0.125f; sc[f*4+r]=v; pmax = fmaxf(pmax,v); }
  pmax = fmaxf(pmax, __shfl_xor(pmax,16,64));
  pmax = fmaxf(pmax, __shfl_xor(pmax,32,64));
  float mnew = fmaxf(mrun, pmax);
  float corr = expf(mrun - mnew);
  float psum = 0.f;
  #pragma unroll
  for (int f=0;f<4;f++){
    u16 pb[4];
    #pragma unroll
    for (int r=0;r<4;r++){ float e = expf(sc[f*4+r]-mnew); psum += e; pb[r] = f2bf(e); }
    unsigned lo = (unsigned)pb[0] | ((unsigned)pb[1]<<16);
    unsigned hi = (unsigned)pb[2] | ((unsigned)pb[3]<<16);
    uint2 pv; pv.x = lo; pv.y = hi;
    *(uint2*)(Plw + m16*72 + f*16 + qd*4) = pv;   // Pl[q][k], k=f*16+qd*4..+3
  }
  psum += __shfl_xor(psum,16,64);
  psum += __shfl_xor(psum,32,64);
  lsum = lsum*corr + psum;
  mrun = mnew;
  float cO[4];
  #pragma unroll
  for (int r=0;r<4;r++) cO[r] = __shfl(corr, qd*4 + r, 64);  // corr for q=qd*4+r
  #pragma unroll
  for (int f2=0;f2<4;f2++)
    #pragma unroll
    for (int r=0;r<4;r++) O[f2][r] *= cO[r];
  #pragma unroll
  for (int b32=0;b32<2;b32++){
    bf16x8 pa = *(const bf16x8*)(Plw + m16*72 + b32*32 + qd*8); // P[q=m16][k-slice]
    #pragma unroll
    for (int f2=0;f2<4;f2++){
      int row = f2*16 + m16;
      bf16x8 vb = *(const bf16x8*)(Vl + row*64 + (((b32<<2)|qd) ^ r7)*8);
      O[f2] = __builtin_amdgcn_mfma_f32_16x16x32_bf16(pa, vb, O[f2], 0,0,0);
    }
  }
}

__global__ __launch_bounds__(256) void flash_k(
    const u16* __restrict__ qkv1, const u16* __restrict__ qkv2,
    const u16* __restrict__ vavgT, u16* __restrict__ outp)
{
  __shared__ __align__(16) u16 K1l[4096];
  __shared__ __align__(16) u16 K2l[4096];
  __shared__ __align__(16) u16 Vl[4096];
  __shared__ __align__(16) u16 Pl[4608];   // 4 waves x [16 q][72]
  int z = blockIdx.y, b = z>>4, h = z&15;
  int q0 = blockIdx.x*64;
  int tid = threadIdx.x, w = tid>>6, l = tid&63;
  int qd = l>>4, m16 = l&15;
  int lr = l>>3;
  int sch = (l&7) ^ lr;
  u16* Plw = Pl + w*1152;

  // Q in registers (B-operand layout): lane holds Q[q0+w*16+m16][dh=qd*8..+8]
  const u16* q1p = qkv1 + ((long)(b*1024 + q0 + w*16 + m16))*3072 + h*64;
  const u16* q2p = qkv2 + ((long)(b*1024 + q0 + w*16 + m16))*3072 + h*64;
  bf16x8 q1a = *(const bf16x8*)(q1p + qd*8);
  bf16x8 q1b = *(const bf16x8*)(q1p + 32 + qd*8);
  bf16x8 q2a = *(const bf16x8*)(q2p + qd*8);
  bf16x8 q2b = *(const bf16x8*)(q2p + 32 + qd*8);

  const u16* k1base = qkv1 + ((long)(b*1024))*3072 + 1024 + h*64;
  const u16* k2base = qkv2 + ((long)(b*1024))*3072 + 1024 + h*64;
  const u16* vbase  = vavgT + (long)z*65536;

  float m1 = -1e30f, l1 = 0.f, m2 = -1e30f, l2 = 0.f;
  f32x4 O1[4], O2[4];
  #pragma unroll
  for (int f=0;f<4;f++){ O1[f]=(f32x4){0.f,0.f,0.f,0.f}; O2[f]=(f32x4){0.f,0.f,0.f,0.f}; }

  for (int t=0;t<16;t++){
    __syncthreads();                      // all waves done reading prev K/V
    #pragma unroll
    for (int c2=0;c2<2;c2++){
      int r = c2*32 + w*8 + lr;
      gload16(k1base + (long)(t*64 + r)*3072 + sch*8, K1l + c2*2048 + w*512);
      gload16(k2base + (long)(t*64 + r)*3072 + sch*8, K2l + c2*2048 + w*512);
      gload16(vbase  + (long)r*1024 + t*64 + sch*8,   Vl  + c2*2048 + w*512);
    }
    __syncthreads();                      // vmcnt drained at barrier
    flash_stream(K1l, Vl, Plw, q1a, q1b, qd, m16, m1, l1, O1);
    flash_stream(K2l, Vl, Plw, q2a, q2b, qd, m16, m2, l2, O2);
  }
  float inv1 = 1.0f/l1, inv2 = 1.0f/l2;
  float i1O[4], i2O[4];
  #pragma unroll
  for (int r=0;r<4;r++){ i1O[r] = __shfl(inv1, qd*4+r, 64); i2O[r] = __shfl(inv2, qd*4+r, 64); }
  #pragma unroll
  for (int f2=0;f2<4;f2++){
    #pragma unroll
    for (int r=0;r<4;r++){
      long idx = ((long)(b*1024 + q0 + w*16 + qd*4 + r))*1024 + h*64 + f2*16 + m16;
      outp[idx] = f2bf(O1[f2][r]*i1O[r] - O2[f2][r]*i2O[r]);
    }
  }
}

// ------------- weight transpose+convert: in [K][N] f32 -> out [N][K] bf16 --
__global__ __launch_bounds__(256) void wtc_k(const float* __restrict__ in,
                                             u16* __restrict__ out, int N, int K){
  __shared__ float tile[64][65];
  int bx = blockIdx.x, by = blockIdx.y;
  int t = threadIdx.x, r = t>>6, c = t&63;
  const float* ip = in + (long)(by*64)*N + bx*64;
  #pragma unroll
  for (int i=0;i<16;i++) tile[i*4+r][c] = ip[(long)(i*4+r)*N + c];
  __syncthreads();
  u16* op = out + (long)(bx*64)*K + by*64;
  #pragma unroll
  for (int i=0;i<16;i++) op[(long)(i*4+r)*K + c] = f2bf(tile[c][i*4+r]);
}

// ---------------- LayerNorm (row over D=1024), f32 in, f32 stats -----------
template<int ACCXC,int HAS_OUT,int OUTF32>
__global__ __launch_bounds__(256) void ln_k(const float* __restrict__ in,
    const float* __restrict__ g, const float* __restrict__ b,
    float* __restrict__ xc, void* __restrict__ out)
{
  __shared__ float sh[4];
  long row = blockIdx.x;
  int tid = threadIdx.x;
  float x[4];
  #pragma unroll
  for (int i=0;i<4;i++) x[i] = in[row*1024 + tid + 256*i];
  float s = x[0]+x[1]+x[2]+x[3];
  float mean = block_sum(s, sh) * (1.0f/1024.0f);
  float ss = 0.f;
  #pragma unroll
  for (int i=0;i<4;i++){ float d = x[i]-mean; ss += d*d; }
  float var = block_sum(ss, sh) * (1.0f/1024.0f);
  float rstd = rsqrtf(var + 1e-5f);
  #pragma unroll
  for (int i=0;i<4;i++){
    int col = tid + 256*i;
    long idx = row*1024 + col;
    float val = (x[i]-mean)*rstd*g[col];
    if (b) val += b[col];
    if (ACCXC) xc[idx] += val;
    if (HAS_OUT){
      if (OUTF32) ((float*)out)[idx] = val;
      else ((u16*)out)[idx] = f2bf(val);
    }
  }
}

__global__ void cvt_k(const float* __restrict__ x, float* __restrict__ xc){
  long i = (long)blockIdx.x*256 + threadIdx.x;
  xc[i] = x[i];
}

__device__ __forceinline__ unsigned avg2(unsigned a, unsigned b){
  u16 r0 = f2bf(0.5f*(bf2f((u16)(a&0xffff)) + bf2f((u16)(b&0xffff))));
  u16 r1 = f2bf(0.5f*(bf2f((u16)(a>>16))    + bf2f((u16)(b>>16))));
  return (unsigned)r0 | ((unsigned)r1<<16);
}

// vavgT[z][dh][s] = 0.5*(v1'+v2'), tiled transpose (coalesced both sides)
__global__ __launch_bounds__(256) void vavg_k(const u16* __restrict__ qkv1,
                                              const u16* __restrict__ qkv2,
                                              u16* __restrict__ vavgT){
  __shared__ u16 tile[64][72];
  int z = blockIdx.y, b = z>>4, h = z&15;
  int s0 = blockIdx.x*64;
  int t = threadIdx.x, r = t>>2, seg = t&3;
  const u16* p1 = qkv1 + ((long)(b*1024 + s0 + r))*3072 + 2048 + h*64 + seg*16;
  const u16* p2 = qkv2 + ((long)(b*1024 + s0 + r))*3072 + 2048 + h*64 + seg*16;
  #pragma unroll
  for (int c=0;c<2;c++){
    uint4 a = *(const uint4*)(p1 + c*8);
    uint4 bb = *(const uint4*)(p2 + c*8);
    uint4 o; o.x = avg2(a.x,bb.x); o.y = avg2(a.y,bb.y); o.z = avg2(a.z,bb.z); o.w = avg2(a.w,bb.w);
    *(uint4*)&tile[r][seg*16 + c*8] = o;
  }
  __syncthreads();
  u16 ov[16];
  #pragma unroll
  for (int j=0;j<16;j++) ov[j] = tile[seg*16+j][r];   // out row dh=r, col s
  uint4 w0, w1;
  w0.x = ov[0]|(ov[1]<<16);  w0.y = ov[2]|(ov[3]<<16);
  w0.z = ov[4]|(ov[5]<<16);  w0.w = ov[6]|(ov[7]<<16);
  w1.x = ov[8]|(ov[9]<<16);  w1.y = ov[10]|(ov[11]<<16);
  w1.z = ov[12]|(ov[13]<<16); w1.w = ov[14]|(ov[15]<<16);
  u16* op = vavgT + (long)z*65536 + (long)r*1024 + s0 + seg*16;
  *(uint4*)op = w0;
  *(uint4*)(op+8) = w1;
}

// abar[d] = b1[d] + sigma_l * sum_r U[d][r] * (sum_j V[r][j])
__global__ void abar_k(const float* __restrict__ sig, const float* __restrict__ U,
                       const float* __restrict__ V, const float* __restrict__ b1,
                       float* __restrict__ abar){
  __shared__ float vs[4];
  int tid = threadIdx.x, w = tid>>6, lane = tid&63;
  float p = 0.f;
  #pragma unroll
  for (int i=0;i<16;i++) p += V[w*1024 + lane + 64*i];
  #pragma unroll
  for (int o=32;o;o>>=1) p += __shfl_down(p,o,64);
  if (lane==0) vs[w] = p;
  __syncthreads();
  float sg = sig[0];
  for (int d=tid; d<1024; d+=256){
    float a = 0.f;
    #pragma unroll
    for (int r=0;r<4;r++) a += U[d*4+r]*vs[r];
    abar[d] = b1[d] + sg*a;
  }
}

// split-K gemv partials: x{1,2}bar = bp{1,2} + abar(half) @ Wp{1,2}
__global__ void bar1p_k(const float* __restrict__ abar,
                        const float* __restrict__ Wp1, const float* __restrict__ Wp2,
                        float* __restrict__ bp){
  int n = blockIdx.x*256 + threadIdx.x;     // grid.x=4
  int kc = blockIdx.y;                      // 16 chunks of 32
  float s1=0.f, s2=0.f;
  for (int j=0;j<32;j++){
    int k = kc*32+j;
    s1 += abar[k]     * Wp1[(long)k*1024 + n];
    s2 += abar[512+k] * Wp2[(long)k*1024 + n];
  }
  bp[kc*2048 + n] = s1; bp[kc*2048 + 1024 + n] = s2;
}
__global__ void bar1r_k(const float* __restrict__ bp,
                        const float* __restrict__ bp1, const float* __restrict__ bp2,
                        float* __restrict__ x1bar, float* __restrict__ x2bar){
  int n = blockIdx.x*256 + threadIdx.x;     // grid 4
  float s1 = bp1[n], s2 = bp2[n];
  for (int kc=0;kc<16;kc++){ s1 += bp[kc*2048+n]; s2 += bp[kc*2048+1024+n]; }
  x1bar[n] = s1; x2bar[n] = s2;
}
// qbias partials: qbar = xbar @ Wq[:, :1024]
__global__ void bar2p_k(const float* __restrict__ xbar, const float* __restrict__ Wq,
                        float* __restrict__ qp){
  int n = blockIdx.x*256 + threadIdx.x;     // grid.x=4 (n<1024)
  int kc = blockIdx.y;                      // 32 chunks of 32
  float s = 0.f;
  for (int j=0;j<32;j++){
    int k = kc*32+j;
    s += xbar[k] * Wq[(long)k*3072 + n];
  }
  qp[kc*1024 + n] = s;
}
__global__ void bar2r_k(const float* __restrict__ qp, float* __restrict__ qbias){
  int m = blockIdx.x*256 + threadIdx.x;     // grid 12 -> 3072
  float s = 0.f;
  if (m < 1024){ for (int kc=0;kc<32;kc++) s += qp[kc*1024 + m]; }
  qbias[m] = s;
}

extern "C" void kernel_launch(void* const* d_in, const int* in_sizes, int n_in,
                              void* d_out, int out_size, void* d_ws, size_t ws_size,
                              hipStream_t stream){
  const float* X    = (const float*)d_in[0];
  const float* SIG  = (const float*)d_in[1];
  const float* U    = (const float*)d_in[2];
  const float* V    = (const float*)d_in[3];
  const float* Wqkv1= (const float*)d_in[4];
  const float* Wqkv2= (const float*)d_in[5];
  const float* Wp1  = (const float*)d_in[6];
  const float* bp1  = (const float*)d_in[7];
  const float* Wp2  = (const float*)d_in[8];
  const float* bp2  = (const float*)d_in[9];
  const float* Wo   = (const float*)d_in[10];
  const float* bo   = (const float*)d_in[11];
  const float* gO   = (const float*)d_in[12];
  const float* bO   = (const float*)d_in[13];
  const float* g1   = (const float*)d_in[14];
  const float* b1   = (const float*)d_in[15];
  const float* g2   = (const float*)d_in[16];
  const float* b2   = (const float*)d_in[17];
  const float* Wm1  = (const float*)d_in[18];
  const float* bm1  = (const float*)d_in[19];
  const float* Wm2  = (const float*)d_in[20];
  const float* bm2  = (const float*)d_in[21];
  const float* gf   = (const float*)d_in[22];
  const float* bfv  = (const float*)d_in[23];
  (void)in_sizes; (void)n_in; (void)out_size; (void)ws_size;

  // ---- workspace layout with time-aliasing (footprint unchanged) ----
  char* p = (char*)d_ws;
  float* xc     = (float*)(p + 0);         // [0, 8M)    residual stream f32
  u16* qkv1     = (u16*)(p + 8388608);     // [8M, 20M)  bf16 (q cols include qbar)
  u16* qkv2     = (u16*)(p + 20971520);    // [20M, 32M) bf16
  u16* bufA     = (u16*)(p + 33554432);    // a_bf / attnout / h2
  u16* bufB     = (u16*)(p + 37748736);    // x1w
  u16* bufC     = (u16*)(p + 41943040);    // x2w / vavgT
  u16* mid      = (u16*)(p + 46137344);    // MLP mid (aliases weight-T region)
  float* projout= (float*)(p + 46137344);  // proj out (aliases weight-T region)
  float* abar   = (float*)(p + 71303168);
  float* x1bar  = (float*)(p + 71307264);
  float* x2bar  = (float*)(p + 71311360);
  // bf16-transposed weights, aliased into time-dead regions:
  u16* wpT1     = (u16*)(p + 46137344);                // 1M
  u16* wpT2     = (u16*)(p + 46137344 + 1048576);      // 1M
  u16* wqkvT1   = (u16*)(p + 46137344 + 2097152);      // 6M
  u16* wqkvT2   = (u16*)(p + 46137344 + 8388608);      // 6M
  float* qbias1 = (float*)(p + 46137344 + 14680064);   // 12K
  float* qbias2 = (float*)(p + 46137344 + 14692352);
  u16* woT      = (u16*)(p + 8388608);                 // 2M (dead qkv1 region post-attn)
  u16* wm1T     = (u16*)(p + 8388608 + 2097152);       // 8M
  u16* wm2T     = (u16*)(p + 8388608 + 10485760);      // 8M
  // gemv partials in the dead former-Pbf region [60M, 68M)
  float* bp     = (float*)(p + 62914560);              // 128K
  float* qp     = (float*)(p + 62914560 + 131072);     // 128K

  u16* a_bf    = bufA; u16* attnout = bufA; u16* h2 = bufA;
  u16* x1w     = bufB;
  u16* x2w     = bufC; u16* vavgT   = bufC;

  cvt_k<<<8192,256,0,stream>>>(X, xc);
  for (int l=0;l<4;l++){
    // exact f32 constant path: abar = b1 + adapt; x{1,2}bar; qbias{1,2}
    abar_k<<<1,256,0,stream>>>(SIG+l, U+(long)l*4096, V+(long)l*4096, b1+l*1024, abar);
    bar1p_k<<<dim3(4,16),256,0,stream>>>(abar, Wp1+(long)l*524288, Wp2+(long)l*524288, bp);
    bar1r_k<<<4,256,0,stream>>>(bp, bp1+l*1024, bp2+l*1024, x1bar, x2bar);
    bar2p_k<<<dim3(4,32),256,0,stream>>>(x1bar, Wqkv1+(long)l*3145728, qp);
    bar2r_k<<<12,256,0,stream>>>(qp, qbias1);
    bar2p_k<<<dim3(4,32),256,0,stream>>>(x2bar, Wqkv2+(long)l*3145728, qp);
    bar2r_k<<<12,256,0,stream>>>(qp, qbias2);
    // weight convert+transpose for the pre-attention GEMMs
    wtc_k<<<dim3(16,8), 256,0,stream>>>(Wp1+(long)l*524288,  wpT1, 1024, 512);
    wtc_k<<<dim3(16,8), 256,0,stream>>>(Wp2+(long)l*524288,  wpT2, 1024, 512);
    wtc_k<<<dim3(48,16),256,0,stream>>>(Wqkv1+(long)l*3145728, wqkvT1, 3072, 1024);
    wtc_k<<<dim3(48,16),256,0,stream>>>(Wqkv2+(long)l*3145728, wqkvT2, 3072, 1024);
    // centered path: a' = LN(xc)*g1 (no beta, no adapt) -> bf16
    ln_k<0,1,0><<<2048,256,0,stream>>>(xc, g1+l*1024, nullptr, nullptr, a_bf);
    // x1' = a'[:, :512] @ Wp1 ; x2' = a'[:, 512:] @ Wp2  (bias folded into bars)
    gemm2_k<2,4,0,0,0><<<dim3(8,32,1),256,0,stream>>>(a_bf,     wpT1, x1w, nullptr,
        512, 1024, 512, 1024, 1.0f, 0, 0,0,0, 0,0,0, 0,0,0);
    gemm2_k<2,4,0,0,0><<<dim3(8,32,1),256,0,stream>>>(a_bf+512, wpT2, x2w, nullptr,
        512, 1024, 512, 1024, 1.0f, 0, 0,0,0, 0,0,0, 0,0,0);
    // qkv' = x' @ Wqkv + [qbar | 0 | 0]
    gemm2_k<4,4,0,0,0><<<dim3(24,16,1),256,0,stream>>>(x1w, wqkvT1, qkv1, qbias1,
        1024, 1024, 1024, 3072, 1.0f, 0, 0,0,0, 0,0,0, 0,0,0);
    gemm2_k<4,4,0,0,0><<<dim3(24,16,1),256,0,stream>>>(x2w, wqkvT2, qkv2, qbias2,
        1024, 1024, 1024, 3072, 1.0f, 0, 0,0,0, 0,0,0, 0,0,0);
    vavg_k<<<dim3(16,32),256,0,stream>>>(qkv1,qkv2,vavgT);
    // fused flash attention: one launch, 512 blocks
    flash_k<<<dim3(16,32),256,0,stream>>>(qkv1, qkv2, vavgT, attnout);
    // convert post-attention weights into the now-dead qkv region
    wtc_k<<<dim3(16,16),256,0,stream>>>(Wo +(long)l*1048576, woT,  1024, 1024);
    wtc_k<<<dim3(64,16),256,0,stream>>>(Wm1+(long)l*4194304, wm1T, 4096, 1024);
    wtc_k<<<dim3(16,64),256,0,stream>>>(Wm2+(long)l*4194304, wm2T, 1024, 4096);
    // proj (f32 out) + LN + residual
    gemm2_k<2,4,1,0,0><<<dim3(8,32,1),256,0,stream>>>(attnout, woT, projout, bo+l*1024,
        1024, 1024, 1024, 1024, 1.0f, 0, 0,0,0, 0,0,0, 0,0,0);
    ln_k<1,0,0><<<2048,256,0,stream>>>(projout, gO+l*1024, bO+l*1024, xc, nullptr);
    // MLP
    ln_k<0,1,0><<<2048,256,0,stream>>>(xc, g2+l*1024, b2+l*1024, nullptr, h2);
    gemm2_k<4,4,0,0,1><<<dim3(32,16,1),256,0,stream>>>(h2, wm1T, mid, bm1+l*4096,
        1024, 1024, 1024, 4096, 1.0f, 0, 0,0,0, 0,0,0, 0,0,0);
    gemm2_k<2,4,1,1,0><<<dim3(8,32,1),256,0,stream>>>(mid, wm2T, (void*)xc, bm2+l*1024,
        4096, 4096, 4096, 1024, 1.0f, 0, 0,0,0, 0,0,0, 0,0,0);
  }
  ln_k<0,1,1><<<2048,256,0,stream>>>(xc, gf, bfv, nullptr, (float*)d_out);
}

// Round 3
// 1514.165 us; speedup vs baseline: 3.3706x; 1.0471x over previous
//
#include <hip/hip_runtime.h>
#include <math.h>

typedef unsigned short u16; // bf16 bits
typedef short bf16x8 __attribute__((ext_vector_type(8)));
typedef float f32x4 __attribute__((ext_vector_type(4)));

__device__ __forceinline__ float bf2f(u16 u){ return __uint_as_float(((unsigned)u)<<16); }
__device__ __forceinline__ u16 f2bf(float f){
  unsigned u = __float_as_uint(f);
  u += 0x7fffu + ((u>>16)&1u);   // RNE
  return (u16)(u>>16);
}
__device__ __forceinline__ float gelu_f(float x){ return 0.5f*x*(1.0f+erff(x*0.7071067811865476f)); }

__device__ __forceinline__ unsigned cvtpk_bf16(float a, float b){
  unsigned r; asm("v_cvt_pk_bf16_f32 %0, %1, %2" : "=v"(r) : "v"(a), "v"(b)); return r;
}

// async global->LDS, 16B per lane; LDS dest = wave-uniform base + lane*16
__device__ __forceinline__ void gload16(const void* g, void* l){
  __builtin_amdgcn_global_load_lds((const __attribute__((address_space(1))) void*)g,
                                   (__attribute__((address_space(3))) void*)l, 16, 0, 0);
}

__device__ __forceinline__ float block_sum(float v, float* sh){
  #pragma unroll
  for (int o=32;o;o>>=1) v += __shfl_down(v,o,64);
  int w = threadIdx.x>>6, lane = threadIdx.x&63;
  __syncthreads();
  if (lane==0) sh[w]=v;
  __syncthreads();
  return sh[0]+sh[1]+sh[2]+sh[3];
}

// ---------------- fast MFMA GEMM: C = act(alpha * A@B^T + bias) -----------
// A [M][K] bf16 (lda), B [N][K] bf16 (ldb).  Tile = (FM*32) x (FN*32), BK=64.
// 4 waves as 2x2; per wave FM x FN fragments of 16x16 (mfma 16x16x32).
// z (blockIdx.z): generic batch via sAz/sBz/sCz element strides; bias + z*biasz.
template<int FM,int FN,int OF32,int ACC,int ACT>
__global__ __launch_bounds__(256) void gemm2_k(
    const u16* __restrict__ A, const u16* __restrict__ Bm, void* __restrict__ Cv,
    const float* __restrict__ bias, int biasz,
    int K,int lda,int ldb,int ldc,float alpha,
    long sAz,long sBz,long sCz)
{
  constexpr int BM = FM*32, BN = FN*32;
  int zz = blockIdx.z;
  const u16* Ap = A  + (long)zz*sAz;
  const u16* Bp = Bm + (long)zz*sBz;
  long coff = (long)zz*sCz;
  int m0 = blockIdx.y*BM, n0 = blockIdx.x*BN;
  __shared__ __align__(16) u16 As[BM][64];
  __shared__ __align__(16) u16 Bs[BN][64];
  u16* AsF = &As[0][0]; u16* BsF = &Bs[0][0];
  int tid = threadIdx.x, w = tid>>6, l = tid&63;
  int q = l>>4, m16 = l&15;
  int wr = w>>1, wc = w&1;
  int sr  = w*8 + (l>>3);              // row within 32-row chunk
  int sch = (l&7) ^ ((l>>3)&7);        // inverse-swizzled source chunk
  int s7  = m16 & 7;                   // read-side row&7

  f32x4 acc[FM][FN];
  #pragma unroll
  for (int i=0;i<FM;i++)
    #pragma unroll
    for (int j=0;j<FN;j++) acc[i][j] = (f32x4){0.f,0.f,0.f,0.f};

  int aRow = wr*(FM*16) + m16;
  int bRow = wc*(FN*16) + m16;

  for (int k0=0;k0<K;k0+=64){
    __syncthreads();
    #pragma unroll
    for (int c=0;c<FM;c++)
      gload16(Ap + (long)(m0 + c*32 + sr)*lda + k0 + sch*8, AsF + c*2048 + w*512);
    #pragma unroll
    for (int c=0;c<FN;c++)
      gload16(Bp + (long)(n0 + c*32 + sr)*ldb + k0 + sch*8, BsF + c*2048 + w*512);
    __syncthreads();
    #pragma unroll
    for (int kh=0;kh<2;kh++){
      bf16x8 afr[FM], bfr[FN];
      #pragma unroll
      for (int i=0;i<FM;i++)
        afr[i] = *(const bf16x8*)(AsF + (aRow + i*16)*64 + (((kh<<2)|q) ^ s7)*8);
      #pragma unroll
      for (int j=0;j<FN;j++)
        bfr[j] = *(const bf16x8*)(BsF + (bRow + j*16)*64 + (((kh<<2)|q) ^ s7)*8);
      #pragma unroll
      for (int i=0;i<FM;i++)
        #pragma unroll
        for (int j=0;j<FN;j++)
          acc[i][j] = __builtin_amdgcn_mfma_f32_16x16x32_bf16(afr[i], bfr[j], acc[i][j], 0,0,0);
    }
  }
  #pragma unroll
  for (int j=0;j<FN;j++){
    int n = n0 + wc*(FN*16) + j*16 + m16;
    float bv = bias ? bias[(long)zz*biasz + n] : 0.0f;
    #pragma unroll
    for (int i=0;i<FM;i++){
      #pragma unroll
      for (int r=0;r<4;r++){
        int m = m0 + wr*(FM*16) + i*16 + q*4 + r;   // C/D: col=lane&15, row=quad*4+reg
        float v = acc[i][j][r]*alpha + bv;
        if (ACT==1) v = gelu_f(v);
        long ci = coff + (long)m*ldc + n;
        if (OF32){
          float* C = (float*)Cv;
          if (ACC) C[ci] += v; else C[ci] = v;
        } else {
          ((u16*)Cv)[ci] = f2bf(v);
        }
      }
    }
  }
}

// ---------------- flash attention: P = sm(Q1K1')-sm(Q2K2'), O = P @ Vavg' --
// base-2 online softmax with defer-max (THR=12 in 2^-domain); per-stream
// normalization at the end; vbar cancels between the two normalized streams.
__device__ __forceinline__ void flash_stream(
    const u16* Kl, const u16* Vl, u16* Plw,
    bf16x8 qa, bf16x8 qb, int qd, int m16,
    float& mrun, float& lsum, f32x4* O)
{
  int r7 = m16 & 7;
  f32x4 s[4];
  __builtin_amdgcn_s_setprio(1);
  #pragma unroll
  for (int f=0;f<4;f++){
    s[f] = (f32x4){0.f,0.f,0.f,0.f};
    int row = f*16 + m16;
    bf16x8 ka = *(const bf16x8*)(Kl + row*64 + ((qd    ) ^ r7)*8);
    bf16x8 kb = *(const bf16x8*)(Kl + row*64 + ((4 + qd) ^ r7)*8);
    s[f] = __builtin_amdgcn_mfma_f32_16x16x32_bf16(ka, qa, s[f], 0,0,0);
    s[f] = __builtin_amdgcn_mfma_f32_16x16x32_bf16(kb, qb, s[f], 0,0,0);
  }
  __builtin_amdgcn_s_setprio(0);
  const float SC2 = 0.18033688011112042f;   // 0.125 * log2(e)
  float sc[16]; float pmax = -1e30f;
  #pragma unroll
  for (int f=0;f<4;f++)
    #pragma unroll
    for (int r=0;r<4;r++){ float v = s[f][r]*SC2; sc[f*4+r]=v; pmax = fmaxf(pmax,v); }
  pmax = fmaxf(pmax, __shfl_xor(pmax,16,64));
  pmax = fmaxf(pmax, __shfl_xor(pmax,32,64));
  bool resc = __any(pmax - mrun > 12.0f);   // wave-uniform branch
  float mnew = resc ? fmaxf(mrun, pmax) : mrun;
  float psum = 0.f;
  #pragma unroll
  for (int f=0;f<4;f++){
    float e0 = exp2f(sc[f*4+0]-mnew), e1 = exp2f(sc[f*4+1]-mnew);
    float e2 = exp2f(sc[f*4+2]-mnew), e3 = exp2f(sc[f*4+3]-mnew);
    psum += (e0+e1)+(e2+e3);
    uint2 pv; pv.x = cvtpk_bf16(e0,e1); pv.y = cvtpk_bf16(e2,e3);
    *(uint2*)(Plw + m16*72 + f*16 + qd*4) = pv;   // Pl[q][k], k=f*16+qd*4..+3
  }
  psum += __shfl_xor(psum,16,64);
  psum += __shfl_xor(psum,32,64);
  if (resc){
    float corr = exp2f(mrun - mnew);
    lsum = lsum*corr + psum;
    mrun = mnew;
    float cO[4];
    #pragma unroll
    for (int r=0;r<4;r++) cO[r] = __shfl(corr, qd*4 + r, 64);
    #pragma unroll
    for (int f2=0;f2<4;f2++)
      #pragma unroll
      for (int r=0;r<4;r++) O[f2][r] *= cO[r];
  } else {
    lsum += psum;
  }
  __builtin_amdgcn_s_setprio(1);
  #pragma unroll
  for (int b32=0;b32<2;b32++){
    bf16x8 pa = *(const bf16x8*)(Plw + m16*72 + b32*32 + qd*8); // P[q=m16][k-slice]
    #pragma unroll
    for (int f2=0;f2<4;f2++){
      int row = f2*16 + m16;
      bf16x8 vb = *(const bf16x8*)(Vl + row*64 + (((b32<<2)|qd) ^ r7)*8);
      O[f2] = __builtin_amdgcn_mfma_f32_16x16x32_bf16(pa, vb, O[f2], 0,0,0);
    }
  }
  __builtin_amdgcn_s_setprio(0);
}

// qkv1/qkv2: [2048 rows][2048 cols] (q|k, bf16, ld 2048); vavgC: [1024 dh][2048 b*s]
__global__ __launch_bounds__(256) void flash_k(
    const u16* __restrict__ qkv1, const u16* __restrict__ qkv2,
    const u16* __restrict__ vavgC, u16* __restrict__ outp)
{
  __shared__ __align__(16) u16 K1l[4096];
  __shared__ __align__(16) u16 K2l[4096];
  __shared__ __align__(16) u16 Vl[4096];
  __shared__ __align__(16) u16 Pl[4608];   // 4 waves x [16 q][72]
  int z = blockIdx.y, b = z>>4, h = z&15;
  int q0 = blockIdx.x*64;
  int tid = threadIdx.x, w = tid>>6, l = tid&63;
  int qd = l>>4, m16 = l&15;
  int lr = l>>3;
  int sch = (l&7) ^ lr;
  u16* Plw = Pl + w*1152;

  // Q in registers (B-operand layout): lane holds Q[q0+w*16+m16][dh=qd*8..+8]
  const u16* q1p = qkv1 + ((long)(b*1024 + q0 + w*16 + m16))*2048 + h*64;
  const u16* q2p = qkv2 + ((long)(b*1024 + q0 + w*16 + m16))*2048 + h*64;
  bf16x8 q1a = *(const bf16x8*)(q1p + qd*8);
  bf16x8 q1b = *(const bf16x8*)(q1p + 32 + qd*8);
  bf16x8 q2a = *(const bf16x8*)(q2p + qd*8);
  bf16x8 q2b = *(const bf16x8*)(q2p + 32 + qd*8);

  const u16* k1base = qkv1 + ((long)(b*1024))*2048 + 1024 + h*64;
  const u16* k2base = qkv2 + ((long)(b*1024))*2048 + 1024 + h*64;
  const u16* vbase  = vavgC + (long)(h*64)*2048 + b*1024;

  float m1 = -1e30f, l1 = 0.f, m2 = -1e30f, l2 = 0.f;
  f32x4 O1[4], O2[4];
  #pragma unroll
  for (int f=0;f<4;f++){ O1[f]=(f32x4){0.f,0.f,0.f,0.f}; O2[f]=(f32x4){0.f,0.f,0.f,0.f}; }

  for (int t=0;t<16;t++){
    __syncthreads();                      // all waves done reading prev K/V
    #pragma unroll
    for (int c2=0;c2<2;c2++){
      int r = c2*32 + w*8 + lr;
      gload16(k1base + (long)(t*64 + r)*2048 + sch*8, K1l + c2*2048 + w*512);
      gload16(k2base + (long)(t*64 + r)*2048 + sch*8, K2l + c2*2048 + w*512);
      gload16(vbase  + (long)r*2048 + t*64 + sch*8,   Vl  + c2*2048 + w*512);
    }
    __syncthreads();                      // vmcnt drained at barrier
    flash_stream(K1l, Vl, Plw, q1a, q1b, qd, m16, m1, l1, O1);
    flash_stream(K2l, Vl, Plw, q2a, q2b, qd, m16, m2, l2, O2);
  }
  float inv1 = 1.0f/l1, inv2 = 1.0f/l2;
  float i1O[4], i2O[4];
  #pragma unroll
  for (int r=0;r<4;r++){ i1O[r] = __shfl(inv1, qd*4+r, 64); i2O[r] = __shfl(inv2, qd*4+r, 64); }
  #pragma unroll
  for (int f2=0;f2<4;f2++){
    #pragma unroll
    for (int r=0;r<4;r++){
      long idx = ((long)(b*1024 + q0 + w*16 + qd*4 + r))*1024 + h*64 + f2*16 + m16;
      outp[idx] = f2bf(O1[f2][r]*i1O[r] - O2[f2][r]*i2O[r]);
    }
  }
}

// ------------- weight transpose+convert: in [K][N] f32 -> out [N][K] bf16 --
// batched via blockIdx.z (in0/out0 vs in1/out1); out row-stride ldout, +koff
__global__ __launch_bounds__(256) void wtc_k(
    const float* __restrict__ in0, const float* __restrict__ in1,
    u16* __restrict__ out0, u16* __restrict__ out1,
    int stride, int ldout, int koff0, int koff1){
  const float* in = blockIdx.z ? in1 : in0;
  u16* out = blockIdx.z ? out1 : out0;
  int koff = blockIdx.z ? koff1 : koff0;
  __shared__ float tile[64][65];
  int bx = blockIdx.x, by = blockIdx.y;
  int t = threadIdx.x, r = t>>6, c = t&63;
  const float* ip = in + (long)(by*64)*stride + bx*64;
  #pragma unroll
  for (int i=0;i<16;i++) tile[i*4+r][c] = ip[(long)(i*4+r)*stride + c];
  __syncthreads();
  u16* op = out + (long)(bx*64)*ldout + by*64 + koff;
  #pragma unroll
  for (int i=0;i<16;i++) op[(long)(i*4+r)*ldout + c] = f2bf(tile[c][i*4+r]);
}

// ---------------- LayerNorm (row over D=1024), f32 in, f32 stats -----------
template<int ACCXC,int HAS_OUT,int OUTF32>
__global__ __launch_bounds__(256) void ln_k(const float* __restrict__ in,
    const float* __restrict__ g, const float* __restrict__ b,
    float* __restrict__ xc, void* __restrict__ out)
{
  __shared__ float sh[4];
  long row = blockIdx.x;
  int tid = threadIdx.x;
  float x[4];
  #pragma unroll
  for (int i=0;i<4;i++) x[i] = in[row*1024 + tid + 256*i];
  float s = x[0]+x[1]+x[2]+x[3];
  float mean = block_sum(s, sh) * (1.0f/1024.0f);
  float ss = 0.f;
  #pragma unroll
  for (int i=0;i<4;i++){ float d = x[i]-mean; ss += d*d; }
  float var = block_sum(ss, sh) * (1.0f/1024.0f);
  float rstd = rsqrtf(var + 1e-5f);
  #pragma unroll
  for (int i=0;i<4;i++){
    int col = tid + 256*i;
    long idx = row*1024 + col;
    float val = (x[i]-mean)*rstd*g[col];
    if (b) val += b[col];
    if (ACCXC) xc[idx] += val;
    if (HAS_OUT){
      if (OUTF32) ((float*)out)[idx] = val;
      else ((u16*)out)[idx] = f2bf(val);
    }
  }
}

__global__ void cvt_k(const float* __restrict__ x, float* __restrict__ xc){
  long i = (long)blockIdx.x*256 + threadIdx.x;
  xc[i] = x[i];
}

// abar[d] = b1[d] + sigma_l * sum_r U[d][r] * (sum_j V[r][j])
__global__ void abar_k(const float* __restrict__ sig, const float* __restrict__ U,
                       const float* __restrict__ V, const float* __restrict__ b1,
                       float* __restrict__ abar){
  __shared__ float vs[4];
  int tid = threadIdx.x, w = tid>>6, lane = tid&63;
  float p = 0.f;
  #pragma unroll
  for (int i=0;i<16;i++) p += V[w*1024 + lane + 64*i];
  #pragma unroll
  for (int o=32;o;o>>=1) p += __shfl_down(p,o,64);
  if (lane==0) vs[w] = p;
  __syncthreads();
  float sg = sig[0];
  for (int d=tid; d<1024; d+=256){
    float a = 0.f;
    #pragma unroll
    for (int r=0;r<4;r++) a += U[d*4+r]*vs[r];
    abar[d] = b1[d] + sg*a;
  }
}

// split-K gemv partials: x{1,2}bar = bp{1,2} + abar(half) @ Wp{1,2}
__global__ void bar1p_k(const float* __restrict__ abar,
                        const float* __restrict__ Wp1, const float* __restrict__ Wp2,
                        float* __restrict__ bp){
  int n = blockIdx.x*256 + threadIdx.x;     // grid.x=4
  int kc = blockIdx.y;                      // 16 chunks of 32
  float s1=0.f, s2=0.f;
  for (int j=0;j<32;j++){
    int k = kc*32+j;
    s1 += abar[k]     * Wp1[(long)k*1024 + n];
    s2 += abar[512+k] * Wp2[(long)k*1024 + n];
  }
  bp[kc*2048 + n] = s1; bp[kc*2048 + 1024 + n] = s2;
}
__global__ void bar1r_k(const float* __restrict__ bp,
                        const float* __restrict__ bp1, const float* __restrict__ bp2,
                        float* __restrict__ x1bar, float* __restrict__ x2bar){
  int n = blockIdx.x*256 + threadIdx.x;     // grid 4
  float s1 = bp1[n], s2 = bp2[n];
  for (int kc=0;kc<16;kc++){ s1 += bp[kc*2048+n]; s2 += bp[kc*2048+1024+n]; }
  x1bar[n] = s1; x2bar[n] = s2;
}
// qbias partials for BOTH streams: qbar_s = x{s}bar @ Wq{s}[:, :1024]
__global__ void bar2p_k(const float* __restrict__ x1bar, const float* __restrict__ x2bar,
                        const float* __restrict__ Wq1, const float* __restrict__ Wq2,
                        float* __restrict__ qp){
  int n = blockIdx.x*256 + threadIdx.x;     // grid.x=4 (n<1024)
  int kc = blockIdx.y;                      // 32 chunks of 32
  float s1 = 0.f, s2 = 0.f;
  for (int j=0;j<32;j++){
    int k = kc*32+j;
    s1 += x1bar[k] * Wq1[(long)k*3072 + n];
    s2 += x2bar[k] * Wq2[(long)k*3072 + n];
  }
  qp[kc*1024 + n] = s1; qp[32768 + kc*1024 + n] = s2;
}
// qbias layout: [stream][2048]; q cols 0..1023 get qbar, k cols 1024..2047 zero
__global__ void bar2r_k(const float* __restrict__ qp, float* __restrict__ qbias){
  int m = blockIdx.x*256 + threadIdx.x;     // grid 16 -> 4096
  int st = m>>11, n = m&2047;
  float s = 0.f;
  if (n < 1024){ for (int kc=0;kc<32;kc++) s += qp[st*32768 + kc*1024 + n]; }
  qbias[m] = s;
}

extern "C" void kernel_launch(void* const* d_in, const int* in_sizes, int n_in,
                              void* d_out, int out_size, void* d_ws, size_t ws_size,
                              hipStream_t stream){
  const float* X    = (const float*)d_in[0];
  const float* SIG  = (const float*)d_in[1];
  const float* U    = (const float*)d_in[2];
  const float* V    = (const float*)d_in[3];
  const float* Wqkv1= (const float*)d_in[4];
  const float* Wqkv2= (const float*)d_in[5];
  const float* Wp1  = (const float*)d_in[6];
  const float* bp1  = (const float*)d_in[7];
  const float* Wp2  = (const float*)d_in[8];
  const float* bp2  = (const float*)d_in[9];
  const float* Wo   = (const float*)d_in[10];
  const float* bo   = (const float*)d_in[11];
  const float* gO   = (const float*)d_in[12];
  const float* bO   = (const float*)d_in[13];
  const float* g1   = (const float*)d_in[14];
  const float* b1   = (const float*)d_in[15];
  const float* g2   = (const float*)d_in[16];
  const float* b2   = (const float*)d_in[17];
  const float* Wm1  = (const float*)d_in[18];
  const float* bm1  = (const float*)d_in[19];
  const float* Wm2  = (const float*)d_in[20];
  const float* bm2  = (const float*)d_in[21];
  const float* gf   = (const float*)d_in[22];
  const float* bfv  = (const float*)d_in[23];
  (void)in_sizes; (void)n_in; (void)out_size; (void)ws_size;

  // ---- workspace layout (64 MiB used; heavy time-aliasing) ----
  const long MB = 1024*1024;
  char* p = (char*)d_ws;
  float* xc    = (float*)(p);              // [0,8M)   residual f32
  u16* qkv1    = (u16*)(p + 8*MB);         // [8,16M)  q|k stream1 [2048][2048]
  u16* qkv2    = (u16*)(p + 16*MB);        // [16,24M) q|k stream2
  u16* bufA    = (u16*)(p + 24*MB);        // [24,28M) a_bf / attnout / h2
  u16* x12w    = (u16*)(p + 28*MB);        // [28,36M) [2048][x1'|x2'] ld 2048
  u16* vavgC   = (u16*)(p + 36*MB);        // [36,40M) [1024 dh][2048 b*s]
  float* bp    = (float*)(p + 36*MB);      //   aliases vavgC (bar phase, pre-vavg)
  float* qp    = (float*)(p + 36*MB + 131072);
  u16* wpT1    = (u16*)(p + 40*MB);        // [40,42M) wpT1|wpT2
  u16* wqkvT1  = (u16*)(p + 42*MB);        // [42,46M) [2048 qk][1024]
  u16* wqkvT2  = (u16*)(p + 46*MB);        // [46,50M)
  u16* wvT12   = (u16*)(p + 50*MB);        // [50,54M) [1024 dh][2048 k-concat]
  u16* mid     = (u16*)(p + 40*MB);        // [40,56M) aliases wT region (MLP phase)
  float* projout=(float*)(p + 56*MB);      // [56,64M)
  float* qbias = (float*)(p + 56*MB);      //   aliases projout (dead by proj time)
  u16* woT     = (u16*)(p + 8*MB);         // post-attn: aliases qkv1
  u16* wm1T    = (u16*)(p + 10*MB);        //   [10,18M)
  u16* wm2T    = (u16*)(p + 28*MB);        //   aliases x12w
  float* abar  = (float*)(p + 64*MB);
  float* x1bar = (float*)(p + 64*MB + 4096);
  float* x2bar = (float*)(p + 64*MB + 8192);

  u16* a_bf = bufA; u16* attnout = bufA; u16* h2 = bufA;
  u16* wpT2 = wpT1 + 524288;

  cvt_k<<<8192,256,0,stream>>>(X, xc);
  for (int l=0;l<4;l++){
    const float* Wqkv1l = Wqkv1+(long)l*3145728;
    const float* Wqkv2l = Wqkv2+(long)l*3145728;
    // exact f32 constant path: abar = b1 + adapt; x{1,2}bar; qbias (both streams)
    abar_k<<<1,256,0,stream>>>(SIG+l, U+(long)l*4096, V+(long)l*4096, b1+l*1024, abar);
    bar1p_k<<<dim3(4,16),256,0,stream>>>(abar, Wp1+(long)l*524288, Wp2+(long)l*524288, bp);
    bar1r_k<<<4,256,0,stream>>>(bp, bp1+l*1024, bp2+l*1024, x1bar, x2bar);
    bar2p_k<<<dim3(4,32),256,0,stream>>>(x1bar, x2bar, Wqkv1l, Wqkv2l, qp);
    bar2r_k<<<16,256,0,stream>>>(qp, qbias);
    // weight convert+transpose (batched): Wp pair, Wqkv q|k pair, Wv pair->concat
    wtc_k<<<dim3(16,8,2), 256,0,stream>>>(Wp1+(long)l*524288, Wp2+(long)l*524288,
                                          wpT1, wpT2, 1024, 512, 0, 0);
    wtc_k<<<dim3(32,16,2),256,0,stream>>>(Wqkv1l, Wqkv2l, wqkvT1, wqkvT2, 3072, 1024, 0, 0);
    wtc_k<<<dim3(16,16,2),256,0,stream>>>(Wqkv1l+2048, Wqkv2l+2048, wvT12, wvT12, 3072, 2048, 0, 1024);
    // centered path: a' = LN(xc)*g1 (no beta, no adapt) -> bf16
    ln_k<0,1,0><<<2048,256,0,stream>>>(xc, g1+l*1024, nullptr, nullptr, a_bf);
    // x1'|x2' = a'[:, :512]@Wp1 | a'[:, 512:]@Wp2  (one z=2 launch, ldc 2048)
    gemm2_k<4,4,0,0,0><<<dim3(8,16,2),256,0,stream>>>(a_bf, wpT1, x12w, nullptr, 0,
        512, 1024, 512, 2048, 1.0f, 512, 524288, 1024);
    // q|k per stream: qkv_s = x_s' @ Wqkv_s[:, :2048] + [qbar_s | 0]
    gemm2_k<4,4,0,0,0><<<dim3(16,16,2),256,0,stream>>>(x12w, wqkvT1, qkv1, qbias, 2048,
        1024, 2048, 1024, 2048, 1.0f, 1024, 2097152, 4194304);
    // vavgC[dh][b*s] = 0.5*(Wv1^T x1' + Wv2^T x2')  (K=2048 concat)
    gemm2_k<4,4,0,0,0><<<dim3(16,8,1),256,0,stream>>>(wvT12, x12w, vavgC, nullptr, 0,
        2048, 2048, 2048, 2048, 0.5f, 0, 0, 0);
    // fused flash attention: one launch, 512 blocks
    flash_k<<<dim3(16,32),256,0,stream>>>(qkv1, qkv2, vavgC, attnout);
    // convert post-attention weights into now-dead regions
    wtc_k<<<dim3(16,16,1),256,0,stream>>>(Wo +(long)l*1048576, nullptr, woT,  nullptr, 1024, 1024, 0, 0);
    wtc_k<<<dim3(64,16,1),256,0,stream>>>(Wm1+(long)l*4194304, nullptr, wm1T, nullptr, 4096, 1024, 0, 0);
    wtc_k<<<dim3(16,64,1),256,0,stream>>>(Wm2+(long)l*4194304, nullptr, wm2T, nullptr, 1024, 4096, 0, 0);
    // proj (f32 out) + LN + residual
    gemm2_k<2,4,1,0,0><<<dim3(8,32,1),256,0,stream>>>(attnout, woT, projout, bo+l*1024, 0,
        1024, 1024, 1024, 1024, 1.0f, 0, 0, 0);
    ln_k<1,0,0><<<2048,256,0,stream>>>(projout, gO+l*1024, bO+l*1024, xc, nullptr);
    // MLP
    ln_k<0,1,0><<<2048,256,0,stream>>>(xc, g2+l*1024, b2+l*1024, nullptr, h2);
    gemm2_k<4,4,0,0,1><<<dim3(32,16,1),256,0,stream>>>(h2, wm1T, mid, bm1+l*4096, 0,
        1024, 1024, 1024, 4096, 1.0f, 0, 0, 0);
    gemm2_k<2,4,1,1,0><<<dim3(8,32,1),256,0,stream>>>(mid, wm2T, (void*)xc, bm2+l*1024, 0,
        4096, 4096, 4096, 1024, 1.0f, 0, 0, 0);
  }
  ln_k<0,1,1><<<2048,256,0,stream>>>(xc, gf, bfv, nullptr, (float*)d_out);
}

// Round 4
// 1379.041 us; speedup vs baseline: 3.7009x; 1.0980x over previous
//
#include <hip/hip_runtime.h>
#include <math.h>

typedef unsigned short u16; // bf16 bits
typedef short bf16x8 __attribute__((ext_vector_type(8)));
typedef float f32x4 __attribute__((ext_vector_type(4)));

__device__ __forceinline__ float bf2f(u16 u){ return __uint_as_float(((unsigned)u)<<16); }
__device__ __forceinline__ u16 f2bf(float f){
  unsigned u = __float_as_uint(f);
  u += 0x7fffu + ((u>>16)&1u);   // RNE
  return (u16)(u>>16);
}
__device__ __forceinline__ float gelu_f(float x){ return 0.5f*x*(1.0f+erff(x*0.7071067811865476f)); }

__device__ __forceinline__ unsigned cvtpk_bf16(float a, float b){
  unsigned r; asm("v_cvt_pk_bf16_f32 %0, %1, %2" : "=v"(r) : "v"(a), "v"(b)); return r;
}

// async global->LDS, 16B per lane; LDS dest = wave-uniform base + lane*16
__device__ __forceinline__ void gload16(const void* g, void* l){
  __builtin_amdgcn_global_load_lds((const __attribute__((address_space(1))) void*)g,
                                   (__attribute__((address_space(3))) void*)l, 16, 0, 0);
}

__device__ __forceinline__ float block_sum(float v, float* sh){
  #pragma unroll
  for (int o=32;o;o>>=1) v += __shfl_down(v,o,64);
  int w = threadIdx.x>>6, lane = threadIdx.x&63;
  __syncthreads();
  if (lane==0) sh[w]=v;
  __syncthreads();
  return sh[0]+sh[1]+sh[2]+sh[3];
}

// ---------------- fast MFMA GEMM: C = act(alpha * A@B^T + bias) -----------
// A [M][K] bf16 (lda), B [N][K] bf16 (ldb).  Tile = (FM*32) x (FN*32), BK=64.
// 2-phase double-buffered pipeline (stage t+1 before compute t, one barrier).
// ACC: 0=store, 1=plain +=, 2=atomicAdd (split-K; bias only on zz==0).
// XCD-chunked bijective swizzle of (bx,by) — requires gx*gy % 8 == 0.
template<int FM,int FN,int OF32,int ACC,int ACT>
__global__ __launch_bounds__(256) void gemm2_k(
    const u16* __restrict__ A, const u16* __restrict__ Bm, void* __restrict__ Cv,
    const float* __restrict__ bias, int biasz,
    int K,int lda,int ldb,int ldc,float alpha,
    long sAz,long sBz,long sCz)
{
  constexpr int BM = FM*32, BN = FN*32;
  int zz = blockIdx.z;
  const u16* Ap = A  + (long)zz*sAz;
  const u16* Bp = Bm + (long)zz*sBz;
  long coff = (long)zz*sCz;
  unsigned nx = gridDim.x, orig = blockIdx.y*nx + blockIdx.x;
  unsigned cpx = (nx*gridDim.y)>>3;
  unsigned swz = (orig&7u)*cpx + (orig>>3);
  int m0 = (int)(swz/nx)*BM, n0 = (int)(swz%nx)*BN;
  __shared__ __align__(16) u16 As[2][BM][64];
  __shared__ __align__(16) u16 Bs[2][BN][64];
  int tid = threadIdx.x, w = tid>>6, l = tid&63;
  int q = l>>4, m16 = l&15;
  int wr = w>>1, wc = w&1;
  int sr  = w*8 + (l>>3);              // staging row within 32-row chunk
  int sch = (l&7) ^ ((l>>3)&7);        // inverse-swizzled source chunk
  int s7  = m16 & 7;                   // read-side row&7

  f32x4 acc[FM][FN];
  #pragma unroll
  for (int i=0;i<FM;i++)
    #pragma unroll
    for (int j=0;j<FN;j++) acc[i][j] = (f32x4){0.f,0.f,0.f,0.f};

  int aRow = wr*(FM*16) + m16;
  int bRow = wc*(FN*16) + m16;
  int nt = K>>6;

  auto STAGE = [&](int t, int buf){
    int k0 = t<<6;
    #pragma unroll
    for (int c=0;c<FM;c++)
      gload16(Ap + (long)(m0 + c*32 + sr)*lda + k0 + sch*8, &As[buf][c*32][0] + w*512);
    #pragma unroll
    for (int c=0;c<FN;c++)
      gload16(Bp + (long)(n0 + c*32 + sr)*ldb + k0 + sch*8, &Bs[buf][c*32][0] + w*512);
  };

  STAGE(0, 0);
  __syncthreads();                         // buf0 ready (vmcnt drained)
  for (int t=0;t<nt;t++){
    int buf = t&1;
    if (t+1<nt) STAGE(t+1, buf^1);         // loads in flight during compute
    const u16* AsF = &As[buf][0][0];
    const u16* BsF = &Bs[buf][0][0];
    __builtin_amdgcn_s_setprio(1);
    #pragma unroll
    for (int kh=0;kh<2;kh++){
      bf16x8 afr[FM], bfr[FN];
      #pragma unroll
      for (int i=0;i<FM;i++)
        afr[i] = *(const bf16x8*)(AsF + (aRow + i*16)*64 + (((kh<<2)|q) ^ s7)*8);
      #pragma unroll
      for (int j=0;j<FN;j++)
        bfr[j] = *(const bf16x8*)(BsF + (bRow + j*16)*64 + (((kh<<2)|q) ^ s7)*8);
      #pragma unroll
      for (int i=0;i<FM;i++)
        #pragma unroll
        for (int j=0;j<FN;j++)
          acc[i][j] = __builtin_amdgcn_mfma_f32_16x16x32_bf16(afr[i], bfr[j], acc[i][j], 0,0,0);
    }
    __builtin_amdgcn_s_setprio(0);
    __syncthreads();                       // next buf ready; cur safe to overwrite
  }
  #pragma unroll
  for (int j=0;j<FN;j++){
    int n = n0 + wc*(FN*16) + j*16 + m16;
    float bv = 0.0f;
    if (bias && (ACC!=2 || zz==0)) bv = bias[(long)zz*biasz + n];
    #pragma unroll
    for (int i=0;i<FM;i++){
      #pragma unroll
      for (int r=0;r<4;r++){
        int m = m0 + wr*(FM*16) + i*16 + q*4 + r;   // C/D: col=lane&15, row=quad*4+reg
        float v = acc[i][j][r]*alpha + bv;
        if (ACT==1) v = gelu_f(v);
        long ci = coff + (long)m*ldc + n;
        if (OF32){
          float* C = (float*)Cv;
          if (ACC==1) C[ci] += v;
          else if (ACC==2) atomicAdd(&C[ci], v);
          else C[ci] = v;
        } else {
          ((u16*)Cv)[ci] = f2bf(v);
        }
      }
    }
  }
}

// ---------------- flash attention: P = sm(Q1K1')-sm(Q2K2'), O = P @ Vavg' --
// base-2 online softmax with defer-max (THR=12 in 2^-domain); per-stream
// normalization at the end; vbar cancels between the two normalized streams.
__device__ __forceinline__ void flash_stream(
    const u16* Kl, const u16* Vl, u16* Plw,
    bf16x8 qa, bf16x8 qb, int qd, int m16,
    float& mrun, float& lsum, f32x4* O)
{
  int r7 = m16 & 7;
  f32x4 s[4];
  __builtin_amdgcn_s_setprio(1);
  #pragma unroll
  for (int f=0;f<4;f++){
    s[f] = (f32x4){0.f,0.f,0.f,0.f};
    int row = f*16 + m16;
    bf16x8 ka = *(const bf16x8*)(Kl + row*64 + ((qd    ) ^ r7)*8);
    bf16x8 kb = *(const bf16x8*)(Kl + row*64 + ((4 + qd) ^ r7)*8);
    s[f] = __builtin_amdgcn_mfma_f32_16x16x32_bf16(ka, qa, s[f], 0,0,0);
    s[f] = __builtin_amdgcn_mfma_f32_16x16x32_bf16(kb, qb, s[f], 0,0,0);
  }
  __builtin_amdgcn_s_setprio(0);
  const float SC2 = 0.18033688011112042f;   // 0.125 * log2(e)
  float sc[16]; float pmax = -1e30f;
  #pragma unroll
  for (int f=0;f<4;f++)
    #pragma unroll
    for (int r=0;r<4;r++){ float v = s[f][r]*SC2; sc[f*4+r]=v; pmax = fmaxf(pmax,v); }
  pmax = fmaxf(pmax, __shfl_xor(pmax,16,64));
  pmax = fmaxf(pmax, __shfl_xor(pmax,32,64));
  bool resc = __any(pmax - mrun > 12.0f);   // wave-uniform branch
  float mnew = resc ? fmaxf(mrun, pmax) : mrun;
  float psum = 0.f;
  #pragma unroll
  for (int f=0;f<4;f++){
    float e0 = exp2f(sc[f*4+0]-mnew), e1 = exp2f(sc[f*4+1]-mnew);
    float e2 = exp2f(sc[f*4+2]-mnew), e3 = exp2f(sc[f*4+3]-mnew);
    psum += (e0+e1)+(e2+e3);
    uint2 pv; pv.x = cvtpk_bf16(e0,e1); pv.y = cvtpk_bf16(e2,e3);
    *(uint2*)(Plw + m16*72 + f*16 + qd*4) = pv;   // Pl[q][k], k=f*16+qd*4..+3
  }
  psum += __shfl_xor(psum,16,64);
  psum += __shfl_xor(psum,32,64);
  if (resc){
    float corr = exp2f(mrun - mnew);
    lsum = lsum*corr + psum;
    mrun = mnew;
    float cO[4];
    #pragma unroll
    for (int r=0;r<4;r++) cO[r] = __shfl(corr, qd*4 + r, 64);
    #pragma unroll
    for (int f2=0;f2<4;f2++)
      #pragma unroll
      for (int r=0;r<4;r++) O[f2][r] *= cO[r];
  } else {
    lsum += psum;
  }
  __builtin_amdgcn_s_setprio(1);
  #pragma unroll
  for (int b32=0;b32<2;b32++){
    bf16x8 pa = *(const bf16x8*)(Plw + m16*72 + b32*32 + qd*8); // P[q=m16][k-slice]
    #pragma unroll
    for (int f2=0;f2<4;f2++){
      int row = f2*16 + m16;
      bf16x8 vb = *(const bf16x8*)(Vl + row*64 + (((b32<<2)|qd) ^ r7)*8);
      O[f2] = __builtin_amdgcn_mfma_f32_16x16x32_bf16(pa, vb, O[f2], 0,0,0);
    }
  }
  __builtin_amdgcn_s_setprio(0);
}

// qkv1/qkv2: [2048 rows][2048 cols] (q|k, bf16, ld 2048); vavgC: [1024 dh][2048 b*s]
__global__ __launch_bounds__(256) void flash_k(
    const u16* __restrict__ qkv1, const u16* __restrict__ qkv2,
    const u16* __restrict__ vavgC, u16* __restrict__ outp)
{
  __shared__ __align__(16) u16 KV[2][3][4096];   // [buf][K1,K2,V]
  __shared__ __align__(16) u16 Pl[4608];         // 4 waves x [16 q][72]
  // XCD swizzle over flattened (x,y): 512 blocks, contiguous q-tiles per XCD
  unsigned nx = gridDim.x, orig = blockIdx.y*nx + blockIdx.x;
  unsigned cpx = (nx*gridDim.y)>>3;
  unsigned swz = (orig&7u)*cpx + (orig>>3);
  int z = (int)(swz/nx), b = z>>4, h = z&15;
  int q0 = (int)(swz%nx)*64;
  int tid = threadIdx.x, w = tid>>6, l = tid&63;
  int qd = l>>4, m16 = l&15;
  int lr = l>>3;
  int sch = (l&7) ^ lr;
  u16* Plw = Pl + w*1152;

  // Q in registers (B-operand layout): lane holds Q[q0+w*16+m16][dh=qd*8..+8]
  const u16* q1p = qkv1 + ((long)(b*1024 + q0 + w*16 + m16))*2048 + h*64;
  const u16* q2p = qkv2 + ((long)(b*1024 + q0 + w*16 + m16))*2048 + h*64;
  bf16x8 q1a = *(const bf16x8*)(q1p + qd*8);
  bf16x8 q1b = *(const bf16x8*)(q1p + 32 + qd*8);
  bf16x8 q2a = *(const bf16x8*)(q2p + qd*8);
  bf16x8 q2b = *(const bf16x8*)(q2p + 32 + qd*8);

  const u16* k1base = qkv1 + ((long)(b*1024))*2048 + 1024 + h*64;
  const u16* k2base = qkv2 + ((long)(b*1024))*2048 + 1024 + h*64;
  const u16* vbase  = vavgC + (long)(h*64)*2048 + b*1024;

  float m1 = -1e30f, l1 = 0.f, m2 = -1e30f, l2 = 0.f;
  f32x4 O1[4], O2[4];
  #pragma unroll
  for (int f=0;f<4;f++){ O1[f]=(f32x4){0.f,0.f,0.f,0.f}; O2[f]=(f32x4){0.f,0.f,0.f,0.f}; }

  auto STAGE = [&](int t, int buf){
    #pragma unroll
    for (int c2=0;c2<2;c2++){
      int r = c2*32 + w*8 + lr;
      gload16(k1base + (long)(t*64 + r)*2048 + sch*8, &KV[buf][0][c2*2048 + w*512]);
      gload16(k2base + (long)(t*64 + r)*2048 + sch*8, &KV[buf][1][c2*2048 + w*512]);
      gload16(vbase  + (long)r*2048 + t*64 + sch*8,   &KV[buf][2][c2*2048 + w*512]);
    }
  };

  STAGE(0, 0);
  __syncthreads();                        // buf0 ready
  for (int t=0;t<16;t++){
    int buf = t&1;
    if (t<15) STAGE(t+1, buf^1);          // prefetch hidden under both streams
    flash_stream(&KV[buf][0][0], &KV[buf][2][0], Plw, q1a, q1b, qd, m16, m1, l1, O1);
    flash_stream(&KV[buf][1][0], &KV[buf][2][0], Plw, q2a, q2b, qd, m16, m2, l2, O2);
    __syncthreads();
  }
  float inv1 = 1.0f/l1, inv2 = 1.0f/l2;
  float i1O[4], i2O[4];
  #pragma unroll
  for (int r=0;r<4;r++){ i1O[r] = __shfl(inv1, qd*4+r, 64); i2O[r] = __shfl(inv2, qd*4+r, 64); }
  #pragma unroll
  for (int f2=0;f2<4;f2++){
    #pragma unroll
    for (int r=0;r<4;r++){
      long idx = ((long)(b*1024 + q0 + w*16 + qd*4 + r))*1024 + h*64 + f2*16 + m16;
      outp[idx] = f2bf(O1[f2][r]*i1O[r] - O2[f2][r]*i2O[r]);
    }
  }
}

// ------------- weight transpose+convert: in [K][N] f32 -> out [N][K] bf16 --
// batched via blockIdx.z (in0/out0 vs in1/out1); out row-stride ldout, +koff
__global__ __launch_bounds__(256) void wtc_k(
    const float* __restrict__ in0, const float* __restrict__ in1,
    u16* __restrict__ out0, u16* __restrict__ out1,
    int stride, int ldout, int koff0, int koff1){
  const float* in = blockIdx.z ? in1 : in0;
  u16* out = blockIdx.z ? out1 : out0;
  int koff = blockIdx.z ? koff1 : koff0;
  __shared__ float tile[64][65];
  int bx = blockIdx.x, by = blockIdx.y;
  int t = threadIdx.x, r = t>>6, c = t&63;
  const float* ip = in + (long)(by*64)*stride + bx*64;
  #pragma unroll
  for (int i=0;i<16;i++) tile[i*4+r][c] = ip[(long)(i*4+r)*stride + c];
  __syncthreads();
  u16* op = out + (long)(bx*64)*ldout + by*64 + koff;
  #pragma unroll
  for (int i=0;i<16;i++) op[(long)(i*4+r)*ldout + c] = f2bf(tile[c][i*4+r]);
}

// ---------------- LayerNorm (row over D=1024), f32 in, f32 stats -----------
template<int ACCXC,int HAS_OUT,int OUTF32>
__global__ __launch_bounds__(256) void ln_k(const float* __restrict__ in,
    const float* __restrict__ g, const float* __restrict__ b,
    float* __restrict__ xc, void* __restrict__ out)
{
  __shared__ float sh[4];
  long row = blockIdx.x;
  int tid = threadIdx.x;
  float x[4];
  #pragma unroll
  for (int i=0;i<4;i++) x[i] = in[row*1024 + tid + 256*i];
  float s = x[0]+x[1]+x[2]+x[3];
  float mean = block_sum(s, sh) * (1.0f/1024.0f);
  float ss = 0.f;
  #pragma unroll
  for (int i=0;i<4;i++){ float d = x[i]-mean; ss += d*d; }
  float var = block_sum(ss, sh) * (1.0f/1024.0f);
  float rstd = rsqrtf(var + 1e-5f);
  #pragma unroll
  for (int i=0;i<4;i++){
    int col = tid + 256*i;
    long idx = row*1024 + col;
    float val = (x[i]-mean)*rstd*g[col];
    if (b) val += b[col];
    if (ACCXC) xc[idx] += val;
    if (HAS_OUT){
      if (OUTF32) ((float*)out)[idx] = val;
      else ((u16*)out)[idx] = f2bf(val);
    }
  }
}

__global__ void cvt_k(const float* __restrict__ x, float* __restrict__ xc){
  long i = (long)blockIdx.x*256 + threadIdx.x;
  xc[i] = x[i];
}

// abar[d] = b1[d] + sigma_l * sum_r U[d][r] * (sum_j V[r][j])
__global__ void abar_k(const float* __restrict__ sig, const float* __restrict__ U,
                       const float* __restrict__ V, const float* __restrict__ b1,
                       float* __restrict__ abar){
  __shared__ float vs[4];
  int tid = threadIdx.x, w = tid>>6, lane = tid&63;
  float p = 0.f;
  #pragma unroll
  for (int i=0;i<16;i++) p += V[w*1024 + lane + 64*i];
  #pragma unroll
  for (int o=32;o;o>>=1) p += __shfl_down(p,o,64);
  if (lane==0) vs[w] = p;
  __syncthreads();
  float sg = sig[0];
  for (int d=tid; d<1024; d+=256){
    float a = 0.f;
    #pragma unroll
    for (int r=0;r<4;r++) a += U[d*4+r]*vs[r];
    abar[d] = b1[d] + sg*a;
  }
}

// split-K gemv partials: x{1,2}bar = bp{1,2} + abar(half) @ Wp{1,2}
__global__ void bar1p_k(const float* __restrict__ abar,
                        const float* __restrict__ Wp1, const float* __restrict__ Wp2,
                        float* __restrict__ bp){
  int n = blockIdx.x*256 + threadIdx.x;     // grid.x=4
  int kc = blockIdx.y;                      // 16 chunks of 32
  float s1=0.f, s2=0.f;
  for (int j=0;j<32;j++){
    int k = kc*32+j;
    s1 += abar[k]     * Wp1[(long)k*1024 + n];
    s2 += abar[512+k] * Wp2[(long)k*1024 + n];
  }
  bp[kc*2048 + n] = s1; bp[kc*2048 + 1024 + n] = s2;
}
__global__ void bar1r_k(const float* __restrict__ bp,
                        const float* __restrict__ bp1, const float* __restrict__ bp2,
                        float* __restrict__ x1bar, float* __restrict__ x2bar){
  int n = blockIdx.x*256 + threadIdx.x;     // grid 4
  float s1 = bp1[n], s2 = bp2[n];
  for (int kc=0;kc<16;kc++){ s1 += bp[kc*2048+n]; s2 += bp[kc*2048+1024+n]; }
  x1bar[n] = s1; x2bar[n] = s2;
}
// qbias partials for BOTH streams: qbar_s = x{s}bar @ Wq{s}[:, :1024]
__global__ void bar2p_k(const float* __restrict__ x1bar, const float* __restrict__ x2bar,
                        const float* __restrict__ Wq1, const float* __restrict__ Wq2,
                        float* __restrict__ qp){
  int n = blockIdx.x*256 + threadIdx.x;     // grid.x=4 (n<1024)
  int kc = blockIdx.y;                      // 32 chunks of 32
  float s1 = 0.f, s2 = 0.f;
  for (int j=0;j<32;j++){
    int k = kc*32+j;
    s1 += x1bar[k] * Wq1[(long)k*3072 + n];
    s2 += x2bar[k] * Wq2[(long)k*3072 + n];
  }
  qp[kc*1024 + n] = s1; qp[32768 + kc*1024 + n] = s2;
}
// qbias layout: [stream][2048]; q cols 0..1023 get qbar, k cols 1024..2047 zero
__global__ void bar2r_k(const float* __restrict__ qp, float* __restrict__ qbias){
  int m = blockIdx.x*256 + threadIdx.x;     // grid 16 -> 4096
  int st = m>>11, n = m&2047;
  float s = 0.f;
  if (n < 1024){ for (int kc=0;kc<32;kc++) s += qp[st*32768 + kc*1024 + n]; }
  qbias[m] = s;
}

extern "C" void kernel_launch(void* const* d_in, const int* in_sizes, int n_in,
                              void* d_out, int out_size, void* d_ws, size_t ws_size,
                              hipStream_t stream){
  const float* X    = (const float*)d_in[0];
  const float* SIG  = (const float*)d_in[1];
  const float* U    = (const float*)d_in[2];
  const float* V    = (const float*)d_in[3];
  const float* Wqkv1= (const float*)d_in[4];
  const float* Wqkv2= (const float*)d_in[5];
  const float* Wp1  = (const float*)d_in[6];
  const float* bp1  = (const float*)d_in[7];
  const float* Wp2  = (const float*)d_in[8];
  const float* bp2  = (const float*)d_in[9];
  const float* Wo   = (const float*)d_in[10];
  const float* bo   = (const float*)d_in[11];
  const float* gO   = (const float*)d_in[12];
  const float* bO   = (const float*)d_in[13];
  const float* g1   = (const float*)d_in[14];
  const float* b1   = (const float*)d_in[15];
  const float* g2   = (const float*)d_in[16];
  const float* b2   = (const float*)d_in[17];
  const float* Wm1  = (const float*)d_in[18];
  const float* bm1  = (const float*)d_in[19];
  const float* Wm2  = (const float*)d_in[20];
  const float* bm2  = (const float*)d_in[21];
  const float* gf   = (const float*)d_in[22];
  const float* bfv  = (const float*)d_in[23];
  (void)in_sizes; (void)n_in; (void)out_size; (void)ws_size;

  // ---- workspace layout (64 MiB used; heavy time-aliasing) ----
  const long MB = 1024*1024;
  char* p = (char*)d_ws;
  float* xc    = (float*)(p);              // [0,8M)   residual f32
  u16* qkv1    = (u16*)(p + 8*MB);         // [8,16M)  q|k stream1 [2048][2048]
  u16* qkv2    = (u16*)(p + 16*MB);        // [16,24M) q|k stream2
  u16* bufA    = (u16*)(p + 24*MB);        // [24,28M) a_bf / attnout / h2
  u16* x12w    = (u16*)(p + 28*MB);        // [28,36M) [2048][x1'|x2'] ld 2048
  u16* vavgC   = (u16*)(p + 36*MB);        // [36,40M) [1024 dh][2048 b*s]
  float* bp    = (float*)(p + 36*MB);      //   aliases vavgC (bar phase, pre-vavg)
  float* qp    = (float*)(p + 36*MB + 131072);
  u16* wpT1    = (u16*)(p + 40*MB);        // [40,42M) wpT1|wpT2
  u16* wqkvT1  = (u16*)(p + 42*MB);        // [42,46M) [2048 qk][1024]
  u16* wqkvT2  = (u16*)(p + 46*MB);        // [46,50M)
  u16* wvT12   = (u16*)(p + 50*MB);        // [50,54M) [1024 dh][2048 k-concat]
  u16* mid     = (u16*)(p + 40*MB);        // [40,56M) aliases wT region (MLP phase)
  float* projout=(float*)(p + 56*MB);      // [56,64M)
  float* qbias = (float*)(p + 56*MB);      //   aliases projout (dead by proj time)
  u16* woT     = (u16*)(p + 8*MB);         // post-attn: aliases qkv1
  u16* wm1T    = (u16*)(p + 10*MB);        //   [10,18M)
  u16* wm2T    = (u16*)(p + 28*MB);        //   aliases x12w
  float* abar  = (float*)(p + 64*MB);
  float* x1bar = (float*)(p + 64*MB + 4096);
  float* x2bar = (float*)(p + 64*MB + 8192);

  u16* a_bf = bufA; u16* attnout = bufA; u16* h2 = bufA;
  u16* wpT2 = wpT1 + 524288;

  cvt_k<<<8192,256,0,stream>>>(X, xc);
  for (int l=0;l<4;l++){
    const float* Wqkv1l = Wqkv1+(long)l*3145728;
    const float* Wqkv2l = Wqkv2+(long)l*3145728;
    // exact f32 constant path: abar = b1 + adapt; x{1,2}bar; qbias (both streams)
    abar_k<<<1,256,0,stream>>>(SIG+l, U+(long)l*4096, V+(long)l*4096, b1+l*1024, abar);
    bar1p_k<<<dim3(4,16),256,0,stream>>>(abar, Wp1+(long)l*524288, Wp2+(long)l*524288, bp);
    bar1r_k<<<4,256,0,stream>>>(bp, bp1+l*1024, bp2+l*1024, x1bar, x2bar);
    bar2p_k<<<dim3(4,32),256,0,stream>>>(x1bar, x2bar, Wqkv1l, Wqkv2l, qp);
    bar2r_k<<<16,256,0,stream>>>(qp, qbias);
    // weight convert+transpose (batched): Wp pair, Wqkv q|k pair, Wv pair->concat
    wtc_k<<<dim3(16,8,2), 256,0,stream>>>(Wp1+(long)l*524288, Wp2+(long)l*524288,
                                          wpT1, wpT2, 1024, 512, 0, 0);
    wtc_k<<<dim3(32,16,2),256,0,stream>>>(Wqkv1l, Wqkv2l, wqkvT1, wqkvT2, 3072, 1024, 0, 0);
    wtc_k<<<dim3(16,16,2),256,0,stream>>>(Wqkv1l+2048, Wqkv2l+2048, wvT12, wvT12, 3072, 2048, 0, 1024);
    // centered path: a' = LN(xc)*g1 (no beta, no adapt) -> bf16
    ln_k<0,1,0><<<2048,256,0,stream>>>(xc, g1+l*1024, nullptr, nullptr, a_bf);
    // x1'|x2' = a'[:, :512]@Wp1 | a'[:, 512:]@Wp2  (one z=2 launch, ldc 2048)
    gemm2_k<2,4,0,0,0><<<dim3(8,32,2),256,0,stream>>>(a_bf, wpT1, x12w, nullptr, 0,
        512, 1024, 512, 2048, 1.0f, 512, 524288, 1024);
    // q|k per stream: qkv_s = x_s' @ Wqkv_s[:, :2048] + [qbar_s | 0]
    gemm2_k<2,4,0,0,0><<<dim3(16,32,2),256,0,stream>>>(x12w, wqkvT1, qkv1, qbias, 2048,
        1024, 2048, 1024, 2048, 1.0f, 1024, 2097152, 4194304);
    // vavgC[dh][b*s] = 0.5*(Wv1^T x1' + Wv2^T x2')  (K=2048 concat)
    gemm2_k<2,2,0,0,0><<<dim3(32,16,1),256,0,stream>>>(wvT12, x12w, vavgC, nullptr, 0,
        2048, 2048, 2048, 2048, 0.5f, 0, 0, 0);
    // fused flash attention: one launch, 512 blocks, 2-phase K/V prefetch
    flash_k<<<dim3(16,32),256,0,stream>>>(qkv1, qkv2, vavgC, attnout);
    // convert post-attention weights into now-dead regions
    wtc_k<<<dim3(16,16,1),256,0,stream>>>(Wo +(long)l*1048576, nullptr, woT,  nullptr, 1024, 1024, 0, 0);
    wtc_k<<<dim3(64,16,1),256,0,stream>>>(Wm1+(long)l*4194304, nullptr, wm1T, nullptr, 4096, 1024, 0, 0);
    wtc_k<<<dim3(16,64,1),256,0,stream>>>(Wm2+(long)l*4194304, nullptr, wm2T, nullptr, 1024, 4096, 0, 0);
    // proj (f32 out) + LN + residual
    gemm2_k<2,2,1,0,0><<<dim3(16,32,1),256,0,stream>>>(attnout, woT, projout, bo+l*1024, 0,
        1024, 1024, 1024, 1024, 1.0f, 0, 0, 0);
    ln_k<1,0,0><<<2048,256,0,stream>>>(projout, gO+l*1024, bO+l*1024, xc, nullptr);
    // MLP
    ln_k<0,1,0><<<2048,256,0,stream>>>(xc, g2+l*1024, b2+l*1024, nullptr, h2);
    gemm2_k<2,4,0,0,1><<<dim3(32,32,1),256,0,stream>>>(h2, wm1T, mid, bm1+l*4096, 0,
        1024, 1024, 1024, 4096, 1.0f, 0, 0, 0);
    // Wm2: split-K z=2 (K=2048 each), atomicAdd into xc; bias only from chunk 0
    gemm2_k<2,4,1,2,0><<<dim3(8,32,2),256,0,stream>>>(mid, wm2T, (void*)xc, bm2+l*1024, 0,
        2048, 4096, 4096, 1024, 1.0f, 2048, 2048, 0);
  }
  ln_k<0,1,1><<<2048,256,0,stream>>>(xc, gf, bfv, nullptr, (float*)d_out);
}